// Round 1
// baseline (1248.206 us; speedup 1.0000x reference)
//
#include <hip/hip_runtime.h>
#include <cstdint>

#define NLAYER 3
#define DMODEL 256
#define NHEAD 8
#define HEADD 32
#define FFDIM 1024
#define BATCH 32
#define SEQ 512
#define MTOK (BATCH*SEQ)   // 16384

typedef __attribute__((ext_vector_type(8))) __bf16 bf16x8;
typedef __attribute__((ext_vector_type(4))) __bf16 bf16x4;
typedef __attribute__((ext_vector_type(4))) float f32x4;

// ---------------------------------------------------------------------------
// Weight prep: fp32 [K][N] -> bf16 [N][K] (transposed), plus QKV bias concat.
// Matrices per layer: Wq,Wk,Wv -> wqkv[l][768][256]; Wo -> wot[l][256][256];
// W1 -> w1t[l][1024][256]; W2 -> w2t[l][256][1024].
// Tiles per layer: 64*3 + 64 + 256 + 256 = 768. 3 layers = 2304 blocks.
// Blocks 2304..2312: bias concat (3 layers * 768 floats).
// ---------------------------------------------------------------------------
__global__ __launch_bounds__(256)
void prep_kernel(const float* __restrict__ Wq, const float* __restrict__ Wk,
                 const float* __restrict__ Wv, const float* __restrict__ Wo,
                 const float* __restrict__ W1, const float* __restrict__ W2,
                 const float* __restrict__ bq, const float* __restrict__ bk,
                 const float* __restrict__ bv,
                 __bf16* __restrict__ wqkv, __bf16* __restrict__ wot,
                 __bf16* __restrict__ w1t, __bf16* __restrict__ w2t,
                 float* __restrict__ bqkv)
{
    const int bid = blockIdx.x;
    const int tid = threadIdx.x;
    if (bid >= 3 * 768) {
        int idx = (bid - 3 * 768) * 256 + tid;  // 0..2303
        int l = idx / 768, j = idx % 768;
        float v = (j < 256) ? bq[l * 256 + j]
                : (j < 512) ? bk[l * 256 + j - 256]
                            : bv[l * 256 + j - 512];
        bqkv[idx] = v;
        return;
    }
    const int l = bid / 768;
    const int rr = bid % 768;
    const float* src; __bf16* dst; int K, N, t;
    if (rr < 192) {
        int ty = rr >> 6; t = rr & 63;
        src = (ty == 0 ? Wq : ty == 1 ? Wk : Wv) + (size_t)l * 65536;
        dst = wqkv + (size_t)l * 768 * 256 + (size_t)ty * 65536;
        K = 256; N = 256;
    } else if (rr < 256) {
        t = rr - 192; src = Wo + (size_t)l * 65536; dst = wot + (size_t)l * 65536;
        K = 256; N = 256;
    } else if (rr < 512) {
        t = rr - 256; src = W1 + (size_t)l * 262144; dst = w1t + (size_t)l * 262144;
        K = 256; N = 1024;
    } else {
        t = rr - 512; src = W2 + (size_t)l * 262144; dst = w2t + (size_t)l * 262144;
        K = 1024; N = 256;
    }
    const int tn = N >> 5;
    const int tk = t / tn, tj = t % tn;
    __shared__ float tile[32][33];
    const int c = tid & 31, rbase = tid >> 5;  // rbase 0..7
#pragma unroll
    for (int p = 0; p < 4; ++p) {
        int kr = rbase + p * 8;
        tile[kr][c] = src[(size_t)(tk * 32 + kr) * N + tj * 32 + c];
    }
    __syncthreads();
#pragma unroll
    for (int p = 0; p < 4; ++p) {
        int nr = rbase + p * 8;
        dst[(size_t)(tj * 32 + nr) * K + tk * 32 + c] = (__bf16)tile[c][nr];
    }
}

// ---------------------------------------------------------------------------
// Input projection: h[m][n] = sum_{k<5} x[m][k]*Win[k][n] + bin[n]  (fp32)
// ---------------------------------------------------------------------------
__global__ __launch_bounds__(256)
void inproj_kernel(const float* __restrict__ x, const float* __restrict__ Win,
                   const float* __restrict__ bin, float* __restrict__ h)
{
    const int m = blockIdx.x;
    const int n = threadIdx.x;
    const float* xr = x + (size_t)m * 5;
    float acc = bin[n];
#pragma unroll
    for (int k = 0; k < 5; ++k) acc += xr[k] * Win[k * DMODEL + n];
    h[(size_t)m * DMODEL + n] = acc;
}

// ---------------------------------------------------------------------------
// MFMA bf16 GEMM: C[M][N] = epilogue(A[M][K] @ Bt[N][K]^T + bias [+ res])
// Bt is bf16 [N][K] (transposed weight). 128x128 tile, BK=32, 256 threads,
// 4 waves in 2x2, each 64x64 via 4x4 mfma_f32_16x16x32_bf16.
// A fragment: lane holds A[m=lane&15][k=(lane>>4)*8 + j]
// B fragment: lane holds B[n=lane&15][k=(lane>>4)*8 + j]   (from Bt rows)
// C/D: col = lane&15, row = (lane>>4)*4 + reg   (verified m89/m91)
// ---------------------------------------------------------------------------
#define LDT 40  // LDS row stride in bf16 elements (80B: 16B-aligned, 2-way banks)

template<int A_BF16, int RELU, int RES, int OBF>
__global__ __launch_bounds__(256)
void gemm_kernel(const void* __restrict__ Av, const __bf16* __restrict__ Bt,
                 const float* __restrict__ bias, const float* __restrict__ res,
                 void* __restrict__ Cv, int M, int N, int K)
{
    const int tid = threadIdx.x;
    const int m0 = blockIdx.x * 128;
    const int n0 = blockIdx.y * 128;
    __shared__ __bf16 As[128 * LDT];
    __shared__ __bf16 Bs[128 * LDT];
    const int lane = tid & 63;
    const int wave = tid >> 6;
    const int wm = (wave & 1) * 64;
    const int wn = (wave >> 1) * 64;
    const int fr = lane & 15;
    const int fq = (lane >> 4) * 8;

    f32x4 acc[4][4];
#pragma unroll
    for (int i = 0; i < 4; ++i)
#pragma unroll
        for (int j = 0; j < 4; ++j)
#pragma unroll
            for (int r = 0; r < 4; ++r) acc[i][j][r] = 0.f;

    for (int k0 = 0; k0 < K; k0 += 32) {
        // ---- stage A tile (128 x 32) into LDS as bf16 ----
        if (A_BF16) {
            const __bf16* A = (const __bf16*)Av;
            const int ar = tid >> 2, ac = (tid & 3) * 8;
#pragma unroll
            for (int p = 0; p < 2; ++p) {
                int row = ar + p * 64;
                bf16x8 v = *(const bf16x8*)(A + (size_t)(m0 + row) * K + k0 + ac);
                *(bf16x8*)(As + row * LDT + ac) = v;
            }
        } else {
            const float* A = (const float*)Av;
            const int ar = tid >> 3, ac = (tid & 7) * 4;
#pragma unroll
            for (int p = 0; p < 4; ++p) {
                int row = ar + p * 32;
                f32x4 v = *(const f32x4*)(A + (size_t)(m0 + row) * K + k0 + ac);
                bf16x4 b;
                b[0] = (__bf16)v[0]; b[1] = (__bf16)v[1];
                b[2] = (__bf16)v[2]; b[3] = (__bf16)v[3];
                *(bf16x4*)(As + row * LDT + ac) = b;
            }
        }
        // ---- stage B tile (128 n x 32 k) from Bt[N][K] ----
        {
            const int br = tid >> 2, bc = (tid & 3) * 8;
#pragma unroll
            for (int p = 0; p < 2; ++p) {
                int row = br + p * 64;
                bf16x8 v = *(const bf16x8*)(Bt + (size_t)(n0 + row) * K + k0 + bc);
                *(bf16x8*)(Bs + row * LDT + bc) = v;
            }
        }
        __syncthreads();
        bf16x8 af[4], bf[4];
#pragma unroll
        for (int i = 0; i < 4; ++i)
            af[i] = *(bf16x8*)(As + (wm + i * 16 + fr) * LDT + fq);
#pragma unroll
        for (int i = 0; i < 4; ++i)
            bf[i] = *(bf16x8*)(Bs + (wn + i * 16 + fr) * LDT + fq);
#pragma unroll
        for (int i = 0; i < 4; ++i)
#pragma unroll
            for (int j = 0; j < 4; ++j)
                acc[i][j] = __builtin_amdgcn_mfma_f32_16x16x32_bf16(
                    af[i], bf[j], acc[i][j], 0, 0, 0);
        __syncthreads();
    }

    // ---- epilogue ----
#pragma unroll
    for (int i = 0; i < 4; ++i) {
#pragma unroll
        for (int j = 0; j < 4; ++j) {
            const int gc = n0 + wn + j * 16 + fr;
            const float bv = bias[gc];
#pragma unroll
            for (int r = 0; r < 4; ++r) {
                const int gr = m0 + wm + i * 16 + (lane >> 4) * 4 + r;
                float v = acc[i][j][r] + bv;
                if (RES) v += res[(size_t)gr * N + gc];
                if (RELU) v = fmaxf(v, 0.f);
                if (OBF) ((__bf16*)Cv)[(size_t)gr * N + gc] = (__bf16)v;
                else     ((float*)Cv)[(size_t)gr * N + gc] = v;
            }
        }
    }
}

// ---------------------------------------------------------------------------
// Attention: one block per (b,h), one thread per query. Two-pass softmax.
// qkv: bf16 [MTOK][768]  (q | k | v). Mask: key j masked out if mask[b][j]!=0.
// Mask is block-uniform -> wave-uniform skip. K/V row loads block-uniform.
// ---------------------------------------------------------------------------
__global__ __launch_bounds__(512)
void attn_kernel(const __bf16* __restrict__ qkv, const int* __restrict__ mask,
                 __bf16* __restrict__ ao)
{
    const int b = blockIdx.x >> 3;
    const int h = blockIdx.x & 7;
    const int s = threadIdx.x;
    const float scale = 0.17677669529663687f;  // 1/sqrt(32)

    const __bf16* qrow = qkv + ((size_t)(b * SEQ + s)) * 768 + h * HEADD;
    float q[HEADD];
#pragma unroll
    for (int i = 0; i < 4; ++i) {
        bf16x8 v = *(const bf16x8*)(qrow + i * 8);
#pragma unroll
        for (int j = 0; j < 8; ++j) q[i * 8 + j] = (float)v[j];
    }
    const int* mrow = mask + b * SEQ;
    const __bf16* kb = qkv + (size_t)b * SEQ * 768 + DMODEL + h * HEADD;
    const __bf16* vb = qkv + (size_t)b * SEQ * 768 + 2 * DMODEL + h * HEADD;

    float mmax = -1e30f, lsum = 0.f;
    for (int j = 0; j < SEQ; ++j) {
        if (mrow[j]) continue;
        const __bf16* kr = kb + (size_t)j * 768;
        float s0 = 0.f, s1 = 0.f, s2 = 0.f, s3 = 0.f;
#pragma unroll
        for (int i = 0; i < 4; ++i) {
            bf16x8 kv = *(const bf16x8*)(kr + i * 8);
            s0 += q[i * 8 + 0] * (float)kv[0] + q[i * 8 + 4] * (float)kv[4];
            s1 += q[i * 8 + 1] * (float)kv[1] + q[i * 8 + 5] * (float)kv[5];
            s2 += q[i * 8 + 2] * (float)kv[2] + q[i * 8 + 6] * (float)kv[6];
            s3 += q[i * 8 + 3] * (float)kv[3] + q[i * 8 + 7] * (float)kv[7];
        }
        float sc = (s0 + s1 + s2 + s3) * scale;
        float mn = fmaxf(mmax, sc);
        lsum = lsum * __expf(mmax - mn) + __expf(sc - mn);
        mmax = mn;
    }

    float o[HEADD];
#pragma unroll
    for (int d = 0; d < HEADD; ++d) o[d] = 0.f;
    for (int j = 0; j < SEQ; ++j) {
        if (mrow[j]) continue;
        const __bf16* kr = kb + (size_t)j * 768;
        float s0 = 0.f, s1 = 0.f, s2 = 0.f, s3 = 0.f;
#pragma unroll
        for (int i = 0; i < 4; ++i) {
            bf16x8 kv = *(const bf16x8*)(kr + i * 8);
            s0 += q[i * 8 + 0] * (float)kv[0] + q[i * 8 + 4] * (float)kv[4];
            s1 += q[i * 8 + 1] * (float)kv[1] + q[i * 8 + 5] * (float)kv[5];
            s2 += q[i * 8 + 2] * (float)kv[2] + q[i * 8 + 6] * (float)kv[6];
            s3 += q[i * 8 + 3] * (float)kv[3] + q[i * 8 + 7] * (float)kv[7];
        }
        float p = __expf((s0 + s1 + s2 + s3) * scale - mmax);
        const __bf16* vr = vb + (size_t)j * 768;
#pragma unroll
        for (int i = 0; i < 4; ++i) {
            bf16x8 vv = *(const bf16x8*)(vr + i * 8);
#pragma unroll
            for (int d = 0; d < 8; ++d) o[i * 8 + d] += p * (float)vv[d];
        }
    }
    const float inv = (lsum > 0.f) ? 1.f / lsum : 0.f;
    __bf16* orow = ao + ((size_t)(b * SEQ + s)) * DMODEL + h * HEADD;
#pragma unroll
    for (int i = 0; i < 4; ++i) {
        bf16x8 w;
#pragma unroll
        for (int d = 0; d < 8; ++d) w[d] = (__bf16)(o[i * 8 + d] * inv);
        *(bf16x8*)(orow + i * 8) = w;
    }
}

// ---------------------------------------------------------------------------
// LayerNorm over 256: one wave per row, 4 elems/lane, shuffle-xor reduce.
// ---------------------------------------------------------------------------
__global__ __launch_bounds__(256)
void ln_kernel(const float* __restrict__ rin, const float* __restrict__ g,
               const float* __restrict__ be, float* __restrict__ out)
{
    const int row = blockIdx.x * 4 + (threadIdx.x >> 6);
    const int lane = threadIdx.x & 63;
    const float* x = rin + (size_t)row * DMODEL + lane * 4;
    f32x4 v = *(const f32x4*)x;
    float s = v[0] + v[1] + v[2] + v[3];
    float ss = v[0] * v[0] + v[1] * v[1] + v[2] * v[2] + v[3] * v[3];
#pragma unroll
    for (int off = 1; off < 64; off <<= 1) {
        s  += __shfl_xor(s, off, 64);
        ss += __shfl_xor(ss, off, 64);
    }
    const float mu = s * (1.f / DMODEL);
    const float var = ss * (1.f / DMODEL) - mu * mu;
    const float rs = rsqrtf(var + 1e-5f);
    f32x4 gv = *(const f32x4*)(g + lane * 4);
    f32x4 bv = *(const f32x4*)(be + lane * 4);
    f32x4 y;
#pragma unroll
    for (int i = 0; i < 4; ++i) y[i] = (v[i] - mu) * rs * gv[i] + bv[i];
    *(f32x4*)(out + (size_t)row * DMODEL + lane * 4) = y;
}

// ---------------------------------------------------------------------------
extern "C" void kernel_launch(void* const* d_in, const int* in_sizes, int n_in,
                              void* d_out, int out_size, void* d_ws, size_t ws_size,
                              hipStream_t stream)
{
    const float* x   = (const float*)d_in[0];
    const int*   mask= (const int*)d_in[1];
    const float* Win = (const float*)d_in[2];
    const float* bin = (const float*)d_in[3];
    const float* Wq  = (const float*)d_in[4];
    const float* bq  = (const float*)d_in[5];
    const float* Wk  = (const float*)d_in[6];
    const float* bk  = (const float*)d_in[7];
    const float* Wv  = (const float*)d_in[8];
    const float* bv  = (const float*)d_in[9];
    const float* Wo  = (const float*)d_in[10];
    const float* bo  = (const float*)d_in[11];
    const float* g1  = (const float*)d_in[12];
    const float* b1  = (const float*)d_in[13];
    const float* W1  = (const float*)d_in[14];
    const float* c1  = (const float*)d_in[15];
    const float* W2  = (const float*)d_in[16];
    const float* c2  = (const float*)d_in[17];
    const float* g2  = (const float*)d_in[18];
    const float* b2  = (const float*)d_in[19];

    char* ws = (char*)d_ws;
    size_t off = 0;
    auto alloc = [&](size_t bytes) -> void* {
        void* p = ws + off;
        off += (bytes + 255) & ~(size_t)255;
        return p;
    };
    float*  h    = (float*)alloc((size_t)MTOK * 256 * 4);   // 16 MB
    float*  rbuf = (float*)alloc((size_t)MTOK * 256 * 4);   // 16 MB
    __bf16* u    = (__bf16*)alloc((size_t)MTOK * 1024 * 2); // 32 MB (qkv / ff union)
    __bf16* qkv  = u;
    __bf16* ffT  = u;
    __bf16* ao   = (__bf16*)alloc((size_t)MTOK * 256 * 2);  // 8 MB
    __bf16* wqkv = (__bf16*)alloc((size_t)3 * 768 * 256 * 2);
    __bf16* wot  = (__bf16*)alloc((size_t)3 * 256 * 256 * 2);
    __bf16* w1t  = (__bf16*)alloc((size_t)3 * 1024 * 256 * 2);
    __bf16* w2t  = (__bf16*)alloc((size_t)3 * 256 * 1024 * 2);
    float*  bqkv = (float*)alloc((size_t)3 * 768 * 4);

    prep_kernel<<<dim3(2313), dim3(256), 0, stream>>>(
        Wq, Wk, Wv, Wo, W1, W2, bq, bk, bv, wqkv, wot, w1t, w2t, bqkv);
    inproj_kernel<<<dim3(MTOK), dim3(256), 0, stream>>>(x, Win, bin, h);

    for (int l = 0; l < NLAYER; ++l) {
        // QKV: [16384,256] @ [256,768] -> bf16 qkv
        gemm_kernel<0, 0, 0, 1><<<dim3(128, 6), dim3(256), 0, stream>>>(
            h, wqkv + (size_t)l * 768 * 256, bqkv + l * 768, nullptr,
            qkv, MTOK, 768, 256);
        // attention
        attn_kernel<<<dim3(256), dim3(512), 0, stream>>>(qkv, mask, ao);
        // Wo + residual: rbuf = h + ao@Wo + bo
        gemm_kernel<1, 0, 1, 0><<<dim3(128, 2), dim3(256), 0, stream>>>(
            ao, wot + (size_t)l * 65536, bo + l * 256, h, rbuf, MTOK, 256, 256);
        // h = LN(rbuf)
        ln_kernel<<<dim3(MTOK / 4), dim3(256), 0, stream>>>(
            rbuf, g1 + l * 256, b1 + l * 256, h);
        // FF1: relu(h@W1 + c1) -> bf16 ffT
        gemm_kernel<0, 1, 0, 1><<<dim3(128, 8), dim3(256), 0, stream>>>(
            h, w1t + (size_t)l * 262144, c1 + l * 1024, nullptr,
            ffT, MTOK, 1024, 256);
        // FF2 + residual: rbuf = h + ffT@W2 + c2
        gemm_kernel<1, 0, 1, 0><<<dim3(128, 2), dim3(256), 0, stream>>>(
            ffT, w2t + (size_t)l * 262144, c2 + l * 256, h, rbuf, MTOK, 256, 1024);
        // h = LN(rbuf)  (last layer writes d_out)
        ln_kernel<<<dim3(MTOK / 4), dim3(256), 0, stream>>>(
            rbuf, g2 + l * 256, b2 + l * 256, (l == 2) ? (float*)d_out : h);
    }
}

// Round 2
// 497.508 us; speedup vs baseline: 2.5089x; 2.5089x over previous
//
#include <hip/hip_runtime.h>
#include <cstdint>

#define NLAYER 3
#define DMODEL 256
#define NHEAD 8
#define HEADD 32
#define FFDIM 1024
#define BATCH 32
#define SEQ 512
#define MTOK (BATCH*SEQ)   // 16384

typedef __attribute__((ext_vector_type(8))) __bf16 bf16x8;
typedef __attribute__((ext_vector_type(4))) __bf16 bf16x4;
typedef __attribute__((ext_vector_type(4))) float f32x4;

// ---------------------------------------------------------------------------
// Weight prep: fp32 [K][N] -> bf16 [N][K] (transposed), plus QKV bias concat.
// ---------------------------------------------------------------------------
__global__ __launch_bounds__(256)
void prep_kernel(const float* __restrict__ Wq, const float* __restrict__ Wk,
                 const float* __restrict__ Wv, const float* __restrict__ Wo,
                 const float* __restrict__ W1, const float* __restrict__ W2,
                 const float* __restrict__ bq, const float* __restrict__ bk,
                 const float* __restrict__ bv,
                 __bf16* __restrict__ wqkv, __bf16* __restrict__ wot,
                 __bf16* __restrict__ w1t, __bf16* __restrict__ w2t,
                 float* __restrict__ bqkv)
{
    const int bid = blockIdx.x;
    const int tid = threadIdx.x;
    if (bid >= 3 * 768) {
        int idx = (bid - 3 * 768) * 256 + tid;  // 0..2303
        int l = idx / 768, j = idx % 768;
        float v = (j < 256) ? bq[l * 256 + j]
                : (j < 512) ? bk[l * 256 + j - 256]
                            : bv[l * 256 + j - 512];
        bqkv[idx] = v;
        return;
    }
    const int l = bid / 768;
    const int rr = bid % 768;
    const float* src; __bf16* dst; int K, N, t;
    if (rr < 192) {
        int ty = rr >> 6; t = rr & 63;
        src = (ty == 0 ? Wq : ty == 1 ? Wk : Wv) + (size_t)l * 65536;
        dst = wqkv + (size_t)l * 768 * 256 + (size_t)ty * 65536;
        K = 256; N = 256;
    } else if (rr < 256) {
        t = rr - 192; src = Wo + (size_t)l * 65536; dst = wot + (size_t)l * 65536;
        K = 256; N = 256;
    } else if (rr < 512) {
        t = rr - 256; src = W1 + (size_t)l * 262144; dst = w1t + (size_t)l * 262144;
        K = 256; N = 1024;
    } else {
        t = rr - 512; src = W2 + (size_t)l * 262144; dst = w2t + (size_t)l * 262144;
        K = 1024; N = 256;
    }
    const int tn = N >> 5;
    const int tk = t / tn, tj = t % tn;
    __shared__ float tile[32][33];
    const int c = tid & 31, rbase = tid >> 5;  // rbase 0..7
#pragma unroll
    for (int p = 0; p < 4; ++p) {
        int kr = rbase + p * 8;
        tile[kr][c] = src[(size_t)(tk * 32 + kr) * N + tj * 32 + c];
    }
    __syncthreads();
#pragma unroll
    for (int p = 0; p < 4; ++p) {
        int nr = rbase + p * 8;
        dst[(size_t)(tj * 32 + nr) * K + tk * 32 + c] = (__bf16)tile[c][nr];
    }
}

// ---------------------------------------------------------------------------
// Input projection: h[m][n] = sum_{k<5} x[m][k]*Win[k][n] + bin[n]  (fp32)
// ---------------------------------------------------------------------------
__global__ __launch_bounds__(256)
void inproj_kernel(const float* __restrict__ x, const float* __restrict__ Win,
                   const float* __restrict__ bin, float* __restrict__ h)
{
    const int m = blockIdx.x;
    const int n = threadIdx.x;
    const float* xr = x + (size_t)m * 5;
    float acc = bin[n];
#pragma unroll
    for (int k = 0; k < 5; ++k) acc += xr[k] * Win[k * DMODEL + n];
    h[(size_t)m * DMODEL + n] = acc;
}

// ---------------------------------------------------------------------------
// MFMA bf16 GEMM (unchanged from round 1): 128x128 tile, BK=32.
// ---------------------------------------------------------------------------
#define LDT 40

template<int A_BF16, int RELU, int RES, int OBF>
__global__ __launch_bounds__(256)
void gemm_kernel(const void* __restrict__ Av, const __bf16* __restrict__ Bt,
                 const float* __restrict__ bias, const float* __restrict__ res,
                 void* __restrict__ Cv, int M, int N, int K)
{
    const int tid = threadIdx.x;
    const int m0 = blockIdx.x * 128;
    const int n0 = blockIdx.y * 128;
    __shared__ __bf16 As[128 * LDT];
    __shared__ __bf16 Bs[128 * LDT];
    const int lane = tid & 63;
    const int wave = tid >> 6;
    const int wm = (wave & 1) * 64;
    const int wn = (wave >> 1) * 64;
    const int fr = lane & 15;
    const int fq = (lane >> 4) * 8;

    f32x4 acc[4][4];
#pragma unroll
    for (int i = 0; i < 4; ++i)
#pragma unroll
        for (int j = 0; j < 4; ++j)
#pragma unroll
            for (int r = 0; r < 4; ++r) acc[i][j][r] = 0.f;

    for (int k0 = 0; k0 < K; k0 += 32) {
        if (A_BF16) {
            const __bf16* A = (const __bf16*)Av;
            const int ar = tid >> 2, ac = (tid & 3) * 8;
#pragma unroll
            for (int p = 0; p < 2; ++p) {
                int row = ar + p * 64;
                bf16x8 v = *(const bf16x8*)(A + (size_t)(m0 + row) * K + k0 + ac);
                *(bf16x8*)(As + row * LDT + ac) = v;
            }
        } else {
            const float* A = (const float*)Av;
            const int ar = tid >> 3, ac = (tid & 7) * 4;
#pragma unroll
            for (int p = 0; p < 4; ++p) {
                int row = ar + p * 32;
                f32x4 v = *(const f32x4*)(A + (size_t)(m0 + row) * K + k0 + ac);
                bf16x4 b;
                b[0] = (__bf16)v[0]; b[1] = (__bf16)v[1];
                b[2] = (__bf16)v[2]; b[3] = (__bf16)v[3];
                *(bf16x4*)(As + row * LDT + ac) = b;
            }
        }
        {
            const int br = tid >> 2, bc = (tid & 3) * 8;
#pragma unroll
            for (int p = 0; p < 2; ++p) {
                int row = br + p * 64;
                bf16x8 v = *(const bf16x8*)(Bt + (size_t)(n0 + row) * K + k0 + bc);
                *(bf16x8*)(Bs + row * LDT + bc) = v;
            }
        }
        __syncthreads();
        bf16x8 af[4], bf[4];
#pragma unroll
        for (int i = 0; i < 4; ++i)
            af[i] = *(bf16x8*)(As + (wm + i * 16 + fr) * LDT + fq);
#pragma unroll
        for (int i = 0; i < 4; ++i)
            bf[i] = *(bf16x8*)(Bs + (wn + i * 16 + fr) * LDT + fq);
#pragma unroll
        for (int i = 0; i < 4; ++i)
#pragma unroll
            for (int j = 0; j < 4; ++j)
                acc[i][j] = __builtin_amdgcn_mfma_f32_16x16x32_bf16(
                    af[i], bf[j], acc[i][j], 0, 0, 0);
        __syncthreads();
    }

#pragma unroll
    for (int i = 0; i < 4; ++i) {
#pragma unroll
        for (int j = 0; j < 4; ++j) {
            const int gc = n0 + wn + j * 16 + fr;
            const float bv = bias[gc];
#pragma unroll
            for (int r = 0; r < 4; ++r) {
                const int gr = m0 + wm + i * 16 + (lane >> 4) * 4 + r;
                float v = acc[i][j][r] + bv;
                if (RES) v += res[(size_t)gr * N + gc];
                if (RELU) v = fmaxf(v, 0.f);
                if (OBF) ((__bf16*)Cv)[(size_t)gr * N + gc] = (__bf16)v;
                else     ((float*)Cv)[(size_t)gr * N + gc] = v;
            }
        }
    }
}

// ---------------------------------------------------------------------------
// MFMA flash attention (transposed formulation).
// Grid: 1024 blocks = (bh * 4 qchunks), 512 threads = 8 waves, 16 q/wave.
// LDS: Ks[512][36] bf16, Vt[32][516] bf16 (V transposed), maskadd[512] f32,
//      Pq: per-wave 16x36 bf16 P-transpose staging. Total 81152 B -> 2 blk/CU.
// S^T tile = mfma(K-rows, Q-rows): D[key][query], col=query=lane&15 ->
//   per-query softmax = in-lane over 8 regs + shfl_xor(16), shfl_xor(32).
// O^T tile = mfma(Vt-rows, P-rows): D[d][query], col=query matches state.
// ---------------------------------------------------------------------------
__global__ __launch_bounds__(512, 4)
void attn_kernel(const __bf16* __restrict__ qkv, const int* __restrict__ mask,
                 __bf16* __restrict__ ao)
{
    __shared__ __bf16 Ks[512 * 36];
    __shared__ __bf16 Vt[32 * 516];
    __shared__ __bf16 Pq[8 * 16 * 36];
    __shared__ float maskadd[512];

    const int qchunk = blockIdx.x & 3;
    const int bh = blockIdx.x >> 2;
    const int b = bh >> 3, h = bh & 7;
    const int t = threadIdx.x;
    const int lane = t & 63, wave = t >> 6;
    const int fr = lane & 15, quad = lane >> 4;
    const float scale = 0.17677669529663687f;  // 1/sqrt(32)

    const size_t qkvbase = (size_t)b * SEQ * 768;

    // ---- stage K (rows) and V (transposed) ----
#pragma unroll
    for (int p = 0; p < 4; ++p) {
        int idx = p * 512 + t;           // 0..2047
        int key = idx >> 2, ch = idx & 3;
        const __bf16* ksrc = qkv + qkvbase + (size_t)key * 768 + 256 + h * 32 + ch * 8;
        bf16x8 kv = *(const bf16x8*)ksrc;
        bf16x4 klo = __builtin_shufflevector(kv, kv, 0, 1, 2, 3);
        bf16x4 khi = __builtin_shufflevector(kv, kv, 4, 5, 6, 7);
        *(bf16x4*)(Ks + key * 36 + ch * 8)     = klo;
        *(bf16x4*)(Ks + key * 36 + ch * 8 + 4) = khi;
        const __bf16* vsrc = qkv + qkvbase + (size_t)key * 768 + 512 + h * 32 + ch * 8;
        bf16x8 vv = *(const bf16x8*)vsrc;
#pragma unroll
        for (int j = 0; j < 8; ++j) Vt[(ch * 8 + j) * 516 + key] = vv[j];
    }
    maskadd[t] = mask[b * SEQ + t] ? -1e30f : 0.f;
    __syncthreads();

    // ---- Q fragment: 16 queries per wave, direct from global ----
    const int q0 = qchunk * 128 + wave * 16;
    bf16x8 qf = *(const bf16x8*)(qkv + qkvbase + (size_t)(q0 + fr) * 768 + h * 32 + quad * 8);

    f32x4 o0 = {0.f, 0.f, 0.f, 0.f}, o1 = {0.f, 0.f, 0.f, 0.f};
    float m = -1e30f, l = 0.f;
    __bf16* Pw = Pq + wave * 16 * 36;

    for (int kt = 0; kt < SEQ; kt += 32) {
        // K fragments (keys kt..kt+15, kt+16..kt+31)
        bf16x4 k0lo = *(bf16x4*)(Ks + (kt + fr) * 36 + quad * 8);
        bf16x4 k0hi = *(bf16x4*)(Ks + (kt + fr) * 36 + quad * 8 + 4);
        bf16x4 k1lo = *(bf16x4*)(Ks + (kt + 16 + fr) * 36 + quad * 8);
        bf16x4 k1hi = *(bf16x4*)(Ks + (kt + 16 + fr) * 36 + quad * 8 + 4);
        bf16x8 kf0 = __builtin_shufflevector(k0lo, k0hi, 0, 1, 2, 3, 4, 5, 6, 7);
        bf16x8 kf1 = __builtin_shufflevector(k1lo, k1hi, 0, 1, 2, 3, 4, 5, 6, 7);
        f32x4 z = {0.f, 0.f, 0.f, 0.f};
        f32x4 s0 = __builtin_amdgcn_mfma_f32_16x16x32_bf16(kf0, qf, z, 0, 0, 0);
        f32x4 s1 = __builtin_amdgcn_mfma_f32_16x16x32_bf16(kf1, qf, z, 0, 0, 0);
        f32x4 ma0 = *(const f32x4*)(maskadd + kt + quad * 4);
        f32x4 ma1 = *(const f32x4*)(maskadd + kt + 16 + quad * 4);
#pragma unroll
        for (int r = 0; r < 4; ++r) {
            s0[r] = s0[r] * scale + ma0[r];
            s1[r] = s1[r] * scale + ma1[r];
        }
        // per-query (col) online softmax
        float tm = fmaxf(fmaxf(fmaxf(s0[0], s0[1]), fmaxf(s0[2], s0[3])),
                         fmaxf(fmaxf(s1[0], s1[1]), fmaxf(s1[2], s1[3])));
        tm = fmaxf(tm, __shfl_xor(tm, 16));
        tm = fmaxf(tm, __shfl_xor(tm, 32));
        float mn = fmaxf(m, tm);
        float alpha = __expf(m - mn);
        float p0[4], p1[4];
        float rs = 0.f;
#pragma unroll
        for (int r = 0; r < 4; ++r) {
            p0[r] = __expf(s0[r] - mn);
            p1[r] = __expf(s1[r] - mn);
            rs += p0[r] + p1[r];
        }
        rs += __shfl_xor(rs, 16);
        rs += __shfl_xor(rs, 32);
        l = l * alpha + rs;
#pragma unroll
        for (int r = 0; r < 4; ++r) { o0[r] *= alpha; o1[r] *= alpha; }
        m = mn;
        // write P^T (4 consecutive keys per reg) to per-wave LDS
        bf16x4 pb0, pb1;
#pragma unroll
        for (int r = 0; r < 4; ++r) { pb0[r] = (__bf16)p0[r]; pb1[r] = (__bf16)p1[r]; }
        *(bf16x4*)(Pw + fr * 36 + quad * 4)      = pb0;
        *(bf16x4*)(Pw + fr * 36 + 16 + quad * 4) = pb1;
        // read back as B-fragment (k = 32 keys of this tile)
        bf16x4 plo = *(bf16x4*)(Pw + fr * 36 + quad * 8);
        bf16x4 phi = *(bf16x4*)(Pw + fr * 36 + quad * 8 + 4);
        bf16x8 pf = __builtin_shufflevector(plo, phi, 0, 1, 2, 3, 4, 5, 6, 7);
        // V^T fragments (d 0..15 and 16..31)
        bf16x4 v0lo = *(bf16x4*)(Vt + fr * 516 + kt + quad * 8);
        bf16x4 v0hi = *(bf16x4*)(Vt + fr * 516 + kt + quad * 8 + 4);
        bf16x4 v1lo = *(bf16x4*)(Vt + (16 + fr) * 516 + kt + quad * 8);
        bf16x4 v1hi = *(bf16x4*)(Vt + (16 + fr) * 516 + kt + quad * 8 + 4);
        bf16x8 vf0 = __builtin_shufflevector(v0lo, v0hi, 0, 1, 2, 3, 4, 5, 6, 7);
        bf16x8 vf1 = __builtin_shufflevector(v1lo, v1hi, 0, 1, 2, 3, 4, 5, 6, 7);
        o0 = __builtin_amdgcn_mfma_f32_16x16x32_bf16(vf0, pf, o0, 0, 0, 0);
        o1 = __builtin_amdgcn_mfma_f32_16x16x32_bf16(vf1, pf, o1, 0, 0, 0);
    }

    // ---- epilogue: normalize, store O (col=query, row=d) ----
    const float inv = (m > -1e29f) ? 1.f / l : 0.f;
    __bf16* orow = ao + (size_t)(b * SEQ + q0 + fr) * DMODEL + h * 32;
    bf16x4 w0, w1;
#pragma unroll
    for (int r = 0; r < 4; ++r) {
        w0[r] = (__bf16)(o0[r] * inv);
        w1[r] = (__bf16)(o1[r] * inv);
    }
    *(bf16x4*)(orow + quad * 4)      = w0;
    *(bf16x4*)(orow + 16 + quad * 4) = w1;
}

// ---------------------------------------------------------------------------
// LayerNorm over 256: one wave per row, 4 elems/lane, shuffle-xor reduce.
// ---------------------------------------------------------------------------
__global__ __launch_bounds__(256)
void ln_kernel(const float* __restrict__ rin, const float* __restrict__ g,
               const float* __restrict__ be, float* __restrict__ out)
{
    const int row = blockIdx.x * 4 + (threadIdx.x >> 6);
    const int lane = threadIdx.x & 63;
    const float* x = rin + (size_t)row * DMODEL + lane * 4;
    f32x4 v = *(const f32x4*)x;
    float s = v[0] + v[1] + v[2] + v[3];
    float ss = v[0] * v[0] + v[1] * v[1] + v[2] * v[2] + v[3] * v[3];
#pragma unroll
    for (int off = 1; off < 64; off <<= 1) {
        s  += __shfl_xor(s, off, 64);
        ss += __shfl_xor(ss, off, 64);
    }
    const float mu = s * (1.f / DMODEL);
    const float var = ss * (1.f / DMODEL) - mu * mu;
    const float rs = rsqrtf(var + 1e-5f);
    f32x4 gv = *(const f32x4*)(g + lane * 4);
    f32x4 bv = *(const f32x4*)(be + lane * 4);
    f32x4 y;
#pragma unroll
    for (int i = 0; i < 4; ++i) y[i] = (v[i] - mu) * rs * gv[i] + bv[i];
    *(f32x4*)(out + (size_t)row * DMODEL + lane * 4) = y;
}

// ---------------------------------------------------------------------------
extern "C" void kernel_launch(void* const* d_in, const int* in_sizes, int n_in,
                              void* d_out, int out_size, void* d_ws, size_t ws_size,
                              hipStream_t stream)
{
    const float* x   = (const float*)d_in[0];
    const int*   mask= (const int*)d_in[1];
    const float* Win = (const float*)d_in[2];
    const float* bin = (const float*)d_in[3];
    const float* Wq  = (const float*)d_in[4];
    const float* bq  = (const float*)d_in[5];
    const float* Wk  = (const float*)d_in[6];
    const float* bk  = (const float*)d_in[7];
    const float* Wv  = (const float*)d_in[8];
    const float* bv  = (const float*)d_in[9];
    const float* Wo  = (const float*)d_in[10];
    const float* bo  = (const float*)d_in[11];
    const float* g1  = (const float*)d_in[12];
    const float* b1  = (const float*)d_in[13];
    const float* W1  = (const float*)d_in[14];
    const float* c1  = (const float*)d_in[15];
    const float* W2  = (const float*)d_in[16];
    const float* c2  = (const float*)d_in[17];
    const float* g2  = (const float*)d_in[18];
    const float* b2  = (const float*)d_in[19];

    char* ws = (char*)d_ws;
    size_t off = 0;
    auto alloc = [&](size_t bytes) -> void* {
        void* p = ws + off;
        off += (bytes + 255) & ~(size_t)255;
        return p;
    };
    float*  h    = (float*)alloc((size_t)MTOK * 256 * 4);   // 16 MB
    float*  rbuf = (float*)alloc((size_t)MTOK * 256 * 4);   // 16 MB
    __bf16* u    = (__bf16*)alloc((size_t)MTOK * 1024 * 2); // 32 MB (qkv / ff union)
    __bf16* qkv  = u;
    __bf16* ffT  = u;
    __bf16* ao   = (__bf16*)alloc((size_t)MTOK * 256 * 2);  // 8 MB
    __bf16* wqkv = (__bf16*)alloc((size_t)3 * 768 * 256 * 2);
    __bf16* wot  = (__bf16*)alloc((size_t)3 * 256 * 256 * 2);
    __bf16* w1t  = (__bf16*)alloc((size_t)3 * 1024 * 256 * 2);
    __bf16* w2t  = (__bf16*)alloc((size_t)3 * 256 * 1024 * 2);
    float*  bqkv = (float*)alloc((size_t)3 * 768 * 4);

    prep_kernel<<<dim3(2313), dim3(256), 0, stream>>>(
        Wq, Wk, Wv, Wo, W1, W2, bq, bk, bv, wqkv, wot, w1t, w2t, bqkv);
    inproj_kernel<<<dim3(MTOK), dim3(256), 0, stream>>>(x, Win, bin, h);

    for (int l = 0; l < NLAYER; ++l) {
        // QKV: [16384,256] @ [256,768] -> bf16 qkv
        gemm_kernel<0, 0, 0, 1><<<dim3(128, 6), dim3(256), 0, stream>>>(
            h, wqkv + (size_t)l * 768 * 256, bqkv + l * 768, nullptr,
            qkv, MTOK, 768, 256);
        // flash attention
        attn_kernel<<<dim3(1024), dim3(512), 0, stream>>>(qkv, mask, ao);
        // Wo + residual: rbuf = h + ao@Wo + bo
        gemm_kernel<1, 0, 1, 0><<<dim3(128, 2), dim3(256), 0, stream>>>(
            ao, wot + (size_t)l * 65536, bo + l * 256, h, rbuf, MTOK, 256, 256);
        // h = LN(rbuf)
        ln_kernel<<<dim3(MTOK / 4), dim3(256), 0, stream>>>(
            rbuf, g1 + l * 256, b1 + l * 256, h);
        // FF1: relu(h@W1 + c1) -> bf16 ffT
        gemm_kernel<0, 1, 0, 1><<<dim3(128, 8), dim3(256), 0, stream>>>(
            h, w1t + (size_t)l * 262144, c1 + l * 1024, nullptr,
            ffT, MTOK, 1024, 256);
        // FF2 + residual: rbuf = h + ffT@W2 + c2
        gemm_kernel<1, 0, 1, 0><<<dim3(128, 2), dim3(256), 0, stream>>>(
            ffT, w2t + (size_t)l * 262144, c2 + l * 256, h, rbuf, MTOK, 256, 1024);
        // h = LN(rbuf)  (last layer writes d_out)
        ln_kernel<<<dim3(MTOK / 4), dim3(256), 0, stream>>>(
            rbuf, g2 + l * 256, b2 + l * 256, (l == 2) ? (float*)d_out : h);
    }
}

// Round 3
// 445.542 us; speedup vs baseline: 2.8015x; 1.1166x over previous
//
#include <hip/hip_runtime.h>
#include <cstdint>

#define NLAYER 3
#define DMODEL 256
#define NHEAD 8
#define HEADD 32
#define FFDIM 1024
#define BATCH 32
#define SEQ 512
#define MTOK (BATCH*SEQ)   // 16384

typedef __attribute__((ext_vector_type(8))) __bf16 bf16x8;
typedef __attribute__((ext_vector_type(4))) __bf16 bf16x4;
typedef __attribute__((ext_vector_type(4))) float f32x4;

typedef __attribute__((address_space(1))) const uint8_t ga_t;
typedef __attribute__((address_space(3))) uint8_t la_t;
__device__ __forceinline__ void gll16(const void* g, void* l) {
    __builtin_amdgcn_global_load_lds((ga_t*)g, (la_t*)l, 16, 0, 0);
}

// ---------------------------------------------------------------------------
// Weight prep: fp32 [K][N] -> bf16 [N][K] (transposed), plus QKV bias concat.
// ---------------------------------------------------------------------------
__global__ __launch_bounds__(256)
void prep_kernel(const float* __restrict__ Wq, const float* __restrict__ Wk,
                 const float* __restrict__ Wv, const float* __restrict__ Wo,
                 const float* __restrict__ W1, const float* __restrict__ W2,
                 const float* __restrict__ bq, const float* __restrict__ bk,
                 const float* __restrict__ bv,
                 __bf16* __restrict__ wqkv, __bf16* __restrict__ wot,
                 __bf16* __restrict__ w1t, __bf16* __restrict__ w2t,
                 float* __restrict__ bqkv)
{
    const int bid = blockIdx.x;
    const int tid = threadIdx.x;
    if (bid >= 3 * 768) {
        int idx = (bid - 3 * 768) * 256 + tid;  // 0..2303
        int l = idx / 768, j = idx % 768;
        float v = (j < 256) ? bq[l * 256 + j]
                : (j < 512) ? bk[l * 256 + j - 256]
                            : bv[l * 256 + j - 512];
        bqkv[idx] = v;
        return;
    }
    const int l = bid / 768;
    const int rr = bid % 768;
    const float* src; __bf16* dst; int K, N, t;
    if (rr < 192) {
        int ty = rr >> 6; t = rr & 63;
        src = (ty == 0 ? Wq : ty == 1 ? Wk : Wv) + (size_t)l * 65536;
        dst = wqkv + (size_t)l * 768 * 256 + (size_t)ty * 65536;
        K = 256; N = 256;
    } else if (rr < 256) {
        t = rr - 192; src = Wo + (size_t)l * 65536; dst = wot + (size_t)l * 65536;
        K = 256; N = 256;
    } else if (rr < 512) {
        t = rr - 256; src = W1 + (size_t)l * 262144; dst = w1t + (size_t)l * 262144;
        K = 256; N = 1024;
    } else {
        t = rr - 512; src = W2 + (size_t)l * 262144; dst = w2t + (size_t)l * 262144;
        K = 1024; N = 256;
    }
    const int tn = N >> 5;
    const int tk = t / tn, tj = t % tn;
    __shared__ float tile[32][33];
    const int c = tid & 31, rbase = tid >> 5;  // rbase 0..7
#pragma unroll
    for (int p = 0; p < 4; ++p) {
        int kr = rbase + p * 8;
        tile[kr][c] = src[(size_t)(tk * 32 + kr) * N + tj * 32 + c];
    }
    __syncthreads();
#pragma unroll
    for (int p = 0; p < 4; ++p) {
        int nr = rbase + p * 8;
        dst[(size_t)(tj * 32 + nr) * K + tk * 32 + c] = (__bf16)tile[c][nr];
    }
}

// ---------------------------------------------------------------------------
// Input projection: h = x@Win + bin, writes fp32 and bf16 copies.
// ---------------------------------------------------------------------------
__global__ __launch_bounds__(256)
void inproj_kernel(const float* __restrict__ x, const float* __restrict__ Win,
                   const float* __restrict__ bin, float* __restrict__ h,
                   __bf16* __restrict__ h16)
{
    const int m = blockIdx.x;
    const int n = threadIdx.x;
    const float* xr = x + (size_t)m * 5;
    float acc = bin[n];
#pragma unroll
    for (int k = 0; k < 5; ++k) acc += xr[k] * Win[k * DMODEL + n];
    h[(size_t)m * DMODEL + n] = acc;
    h16[(size_t)m * DMODEL + n] = (__bf16)acc;
}

// ---------------------------------------------------------------------------
// MFMA bf16 GEMM with global_load_lds staging + XOR chunk swizzle.
// C[M][N] = epi(A[M][K](bf16) @ Bt[N][K]^T + bias [+ res(fp32)])
// 128x128 tile, BK=64, 256 threads (4 waves, 2x2 of 64x64).
// LDS tiles unpadded (required by global_load_lds); 16B chunk q of row r is
// stored at chunk position q ^ (r&7)  -> fragment reads are ~conflict-free.
// ---------------------------------------------------------------------------
template<int RELU, int RES, int OBF>
__global__ __launch_bounds__(256, 2)
void gemm_kernel(const __bf16* __restrict__ A, const __bf16* __restrict__ Bt,
                 const float* __restrict__ bias, const float* __restrict__ res,
                 void* __restrict__ Cv, int M, int N, int K)
{
    __shared__ __bf16 As[128 * 64];
    __shared__ __bf16 Bs[128 * 64];
    const int tid = threadIdx.x;
    const int m0 = blockIdx.x * 128;
    const int n0 = blockIdx.y * 128;
    const int lane = tid & 63;
    const int wave = tid >> 6;
    const int wm = (wave & 1) * 64;
    const int wn = (wave >> 1) * 64;
    const int fr = lane & 15;
    const int quad = lane >> 4;
    const int lr = lane >> 3;             // row-within-8 for staging
    const int qg = (lane & 7) ^ lr;       // swizzled source chunk

    // per-lane global base (k0 added in loop); wave w stages rows w*32..w*32+31
    const __bf16* Ab = A  + (size_t)(m0 + wave * 32 + lr) * K + qg * 8;
    const __bf16* Bb = Bt + (size_t)(n0 + wave * 32 + lr) * K + qg * 8;

    f32x4 acc[4][4];
#pragma unroll
    for (int i = 0; i < 4; ++i)
#pragma unroll
        for (int j = 0; j < 4; ++j)
#pragma unroll
            for (int r = 0; r < 4; ++r) acc[i][j][r] = 0.f;

    const int frs = fr & 7;

    for (int k0 = 0; k0 < K; k0 += 64) {
#pragma unroll
        for (int j = 0; j < 4; ++j) {
            gll16(Ab + (size_t)j * 8 * K + k0, As + (wave * 4 + j) * 512);
            gll16(Bb + (size_t)j * 8 * K + k0, Bs + (wave * 4 + j) * 512);
        }
        __syncthreads();
#pragma unroll
        for (int kk = 0; kk < 2; ++kk) {
            bf16x8 af[4], bfr[4];
#pragma unroll
            for (int i = 0; i < 4; ++i) {
                int row = wm + i * 16 + fr;
                af[i] = *(const bf16x8*)(As + row * 64 + (((kk * 4 + quad) ^ frs) * 8));
            }
#pragma unroll
            for (int j = 0; j < 4; ++j) {
                int row = wn + j * 16 + fr;
                bfr[j] = *(const bf16x8*)(Bs + row * 64 + (((kk * 4 + quad) ^ frs) * 8));
            }
#pragma unroll
            for (int i = 0; i < 4; ++i)
#pragma unroll
                for (int j = 0; j < 4; ++j)
                    acc[i][j] = __builtin_amdgcn_mfma_f32_16x16x32_bf16(
                        af[i], bfr[j], acc[i][j], 0, 0, 0);
        }
        __syncthreads();
    }

    // ---- epilogue ----
#pragma unroll
    for (int i = 0; i < 4; ++i) {
#pragma unroll
        for (int j = 0; j < 4; ++j) {
            const int gc = n0 + wn + j * 16 + fr;
            const float bv = bias[gc];
#pragma unroll
            for (int r = 0; r < 4; ++r) {
                const int gr = m0 + wm + i * 16 + quad * 4 + r;
                float v = acc[i][j][r] + bv;
                if (RES) v += res[(size_t)gr * N + gc];
                if (RELU) v = fmaxf(v, 0.f);
                if (OBF) ((__bf16*)Cv)[(size_t)gr * N + gc] = (__bf16)v;
                else     ((float*)Cv)[(size_t)gr * N + gc] = v;
            }
        }
    }
}

// ---------------------------------------------------------------------------
// MFMA flash attention (transposed formulation) — unchanged from round 2.
// ---------------------------------------------------------------------------
__global__ __launch_bounds__(512, 4)
void attn_kernel(const __bf16* __restrict__ qkv, const int* __restrict__ mask,
                 __bf16* __restrict__ ao)
{
    __shared__ __bf16 Ks[512 * 36];
    __shared__ __bf16 Vt[32 * 516];
    __shared__ __bf16 Pq[8 * 16 * 36];
    __shared__ float maskadd[512];

    const int qchunk = blockIdx.x & 3;
    const int bh = blockIdx.x >> 2;
    const int b = bh >> 3, h = bh & 7;
    const int t = threadIdx.x;
    const int lane = t & 63, wave = t >> 6;
    const int fr = lane & 15, quad = lane >> 4;
    const float scale = 0.17677669529663687f;  // 1/sqrt(32)

    const size_t qkvbase = (size_t)b * SEQ * 768;

#pragma unroll
    for (int p = 0; p < 4; ++p) {
        int idx = p * 512 + t;           // 0..2047
        int key = idx >> 2, ch = idx & 3;
        const __bf16* ksrc = qkv + qkvbase + (size_t)key * 768 + 256 + h * 32 + ch * 8;
        bf16x8 kv = *(const bf16x8*)ksrc;
        bf16x4 klo = __builtin_shufflevector(kv, kv, 0, 1, 2, 3);
        bf16x4 khi = __builtin_shufflevector(kv, kv, 4, 5, 6, 7);
        *(bf16x4*)(Ks + key * 36 + ch * 8)     = klo;
        *(bf16x4*)(Ks + key * 36 + ch * 8 + 4) = khi;
        const __bf16* vsrc = qkv + qkvbase + (size_t)key * 768 + 512 + h * 32 + ch * 8;
        bf16x8 vv = *(const bf16x8*)vsrc;
#pragma unroll
        for (int j = 0; j < 8; ++j) Vt[(ch * 8 + j) * 516 + key] = vv[j];
    }
    maskadd[t] = mask[b * SEQ + t] ? -1e30f : 0.f;
    __syncthreads();

    const int q0 = qchunk * 128 + wave * 16;
    bf16x8 qf = *(const bf16x8*)(qkv + qkvbase + (size_t)(q0 + fr) * 768 + h * 32 + quad * 8);

    f32x4 o0 = {0.f, 0.f, 0.f, 0.f}, o1 = {0.f, 0.f, 0.f, 0.f};
    float m = -1e30f, l = 0.f;
    __bf16* Pw = Pq + wave * 16 * 36;

    for (int kt = 0; kt < SEQ; kt += 32) {
        bf16x4 k0lo = *(bf16x4*)(Ks + (kt + fr) * 36 + quad * 8);
        bf16x4 k0hi = *(bf16x4*)(Ks + (kt + fr) * 36 + quad * 8 + 4);
        bf16x4 k1lo = *(bf16x4*)(Ks + (kt + 16 + fr) * 36 + quad * 8);
        bf16x4 k1hi = *(bf16x4*)(Ks + (kt + 16 + fr) * 36 + quad * 8 + 4);
        bf16x8 kf0 = __builtin_shufflevector(k0lo, k0hi, 0, 1, 2, 3, 4, 5, 6, 7);
        bf16x8 kf1 = __builtin_shufflevector(k1lo, k1hi, 0, 1, 2, 3, 4, 5, 6, 7);
        f32x4 z = {0.f, 0.f, 0.f, 0.f};
        f32x4 s0 = __builtin_amdgcn_mfma_f32_16x16x32_bf16(kf0, qf, z, 0, 0, 0);
        f32x4 s1 = __builtin_amdgcn_mfma_f32_16x16x32_bf16(kf1, qf, z, 0, 0, 0);
        f32x4 ma0 = *(const f32x4*)(maskadd + kt + quad * 4);
        f32x4 ma1 = *(const f32x4*)(maskadd + kt + 16 + quad * 4);
#pragma unroll
        for (int r = 0; r < 4; ++r) {
            s0[r] = s0[r] * scale + ma0[r];
            s1[r] = s1[r] * scale + ma1[r];
        }
        float tm = fmaxf(fmaxf(fmaxf(s0[0], s0[1]), fmaxf(s0[2], s0[3])),
                         fmaxf(fmaxf(s1[0], s1[1]), fmaxf(s1[2], s1[3])));
        tm = fmaxf(tm, __shfl_xor(tm, 16));
        tm = fmaxf(tm, __shfl_xor(tm, 32));
        float mn = fmaxf(m, tm);
        float alpha = __expf(m - mn);
        float p0[4], p1[4];
        float rs = 0.f;
#pragma unroll
        for (int r = 0; r < 4; ++r) {
            p0[r] = __expf(s0[r] - mn);
            p1[r] = __expf(s1[r] - mn);
            rs += p0[r] + p1[r];
        }
        rs += __shfl_xor(rs, 16);
        rs += __shfl_xor(rs, 32);
        l = l * alpha + rs;
#pragma unroll
        for (int r = 0; r < 4; ++r) { o0[r] *= alpha; o1[r] *= alpha; }
        m = mn;
        bf16x4 pb0, pb1;
#pragma unroll
        for (int r = 0; r < 4; ++r) { pb0[r] = (__bf16)p0[r]; pb1[r] = (__bf16)p1[r]; }
        *(bf16x4*)(Pw + fr * 36 + quad * 4)      = pb0;
        *(bf16x4*)(Pw + fr * 36 + 16 + quad * 4) = pb1;
        bf16x4 plo = *(bf16x4*)(Pw + fr * 36 + quad * 8);
        bf16x4 phi = *(bf16x4*)(Pw + fr * 36 + quad * 8 + 4);
        bf16x8 pf = __builtin_shufflevector(plo, phi, 0, 1, 2, 3, 4, 5, 6, 7);
        bf16x4 v0lo = *(bf16x4*)(Vt + fr * 516 + kt + quad * 8);
        bf16x4 v0hi = *(bf16x4*)(Vt + fr * 516 + kt + quad * 8 + 4);
        bf16x4 v1lo = *(bf16x4*)(Vt + (16 + fr) * 516 + kt + quad * 8);
        bf16x4 v1hi = *(bf16x4*)(Vt + (16 + fr) * 516 + kt + quad * 8 + 4);
        bf16x8 vf0 = __builtin_shufflevector(v0lo, v0hi, 0, 1, 2, 3, 4, 5, 6, 7);
        bf16x8 vf1 = __builtin_shufflevector(v1lo, v1hi, 0, 1, 2, 3, 4, 5, 6, 7);
        o0 = __builtin_amdgcn_mfma_f32_16x16x32_bf16(vf0, pf, o0, 0, 0, 0);
        o1 = __builtin_amdgcn_mfma_f32_16x16x32_bf16(vf1, pf, o1, 0, 0, 0);
    }

    const float inv = (m > -1e29f) ? 1.f / l : 0.f;
    __bf16* orow = ao + (size_t)(b * SEQ + q0 + fr) * DMODEL + h * 32;
    bf16x4 w0, w1;
#pragma unroll
    for (int r = 0; r < 4; ++r) {
        w0[r] = (__bf16)(o0[r] * inv);
        w1[r] = (__bf16)(o1[r] * inv);
    }
    *(bf16x4*)(orow + quad * 4)      = w0;
    *(bf16x4*)(orow + 16 + quad * 4) = w1;
}

// ---------------------------------------------------------------------------
// LayerNorm over 256: one wave per row; writes fp32 and optional bf16 copy.
// ---------------------------------------------------------------------------
__global__ __launch_bounds__(256)
void ln_kernel(const float* __restrict__ rin, const float* __restrict__ g,
               const float* __restrict__ be, float* __restrict__ out,
               __bf16* __restrict__ out16)
{
    const int row = blockIdx.x * 4 + (threadIdx.x >> 6);
    const int lane = threadIdx.x & 63;
    const float* x = rin + (size_t)row * DMODEL + lane * 4;
    f32x4 v = *(const f32x4*)x;
    float s = v[0] + v[1] + v[2] + v[3];
    float ss = v[0] * v[0] + v[1] * v[1] + v[2] * v[2] + v[3] * v[3];
#pragma unroll
    for (int off = 1; off < 64; off <<= 1) {
        s  += __shfl_xor(s, off, 64);
        ss += __shfl_xor(ss, off, 64);
    }
    const float mu = s * (1.f / DMODEL);
    const float var = ss * (1.f / DMODEL) - mu * mu;
    const float rs = rsqrtf(var + 1e-5f);
    f32x4 gv = *(const f32x4*)(g + lane * 4);
    f32x4 bv = *(const f32x4*)(be + lane * 4);
    f32x4 y;
#pragma unroll
    for (int i = 0; i < 4; ++i) y[i] = (v[i] - mu) * rs * gv[i] + bv[i];
    *(f32x4*)(out + (size_t)row * DMODEL + lane * 4) = y;
    if (out16) {
        bf16x4 yb;
#pragma unroll
        for (int i = 0; i < 4; ++i) yb[i] = (__bf16)y[i];
        *(bf16x4*)(out16 + (size_t)row * DMODEL + lane * 4) = yb;
    }
}

// ---------------------------------------------------------------------------
extern "C" void kernel_launch(void* const* d_in, const int* in_sizes, int n_in,
                              void* d_out, int out_size, void* d_ws, size_t ws_size,
                              hipStream_t stream)
{
    const float* x   = (const float*)d_in[0];
    const int*   mask= (const int*)d_in[1];
    const float* Win = (const float*)d_in[2];
    const float* bin = (const float*)d_in[3];
    const float* Wq  = (const float*)d_in[4];
    const float* bq  = (const float*)d_in[5];
    const float* Wk  = (const float*)d_in[6];
    const float* bk  = (const float*)d_in[7];
    const float* Wv  = (const float*)d_in[8];
    const float* bv  = (const float*)d_in[9];
    const float* Wo  = (const float*)d_in[10];
    const float* bo  = (const float*)d_in[11];
    const float* g1  = (const float*)d_in[12];
    const float* b1  = (const float*)d_in[13];
    const float* W1  = (const float*)d_in[14];
    const float* c1  = (const float*)d_in[15];
    const float* W2  = (const float*)d_in[16];
    const float* c2  = (const float*)d_in[17];
    const float* g2  = (const float*)d_in[18];
    const float* b2  = (const float*)d_in[19];

    char* ws = (char*)d_ws;
    size_t off = 0;
    auto alloc = [&](size_t bytes) -> void* {
        void* p = ws + off;
        off += (bytes + 255) & ~(size_t)255;
        return p;
    };
    float*  h    = (float*)alloc((size_t)MTOK * 256 * 4);   // 16 MB
    __bf16* h16  = (__bf16*)alloc((size_t)MTOK * 256 * 2);  // 8 MB
    float*  rbuf = (float*)alloc((size_t)MTOK * 256 * 4);   // 16 MB
    __bf16* u    = (__bf16*)alloc((size_t)MTOK * 1024 * 2); // 32 MB (qkv / ff union)
    __bf16* qkv  = u;
    __bf16* ffT  = u;
    __bf16* ao   = (__bf16*)alloc((size_t)MTOK * 256 * 2);  // 8 MB
    __bf16* wqkv = (__bf16*)alloc((size_t)3 * 768 * 256 * 2);
    __bf16* wot  = (__bf16*)alloc((size_t)3 * 256 * 256 * 2);
    __bf16* w1t  = (__bf16*)alloc((size_t)3 * 1024 * 256 * 2);
    __bf16* w2t  = (__bf16*)alloc((size_t)3 * 256 * 1024 * 2);
    float*  bqkv = (float*)alloc((size_t)3 * 768 * 4);

    prep_kernel<<<dim3(2313), dim3(256), 0, stream>>>(
        Wq, Wk, Wv, Wo, W1, W2, bq, bk, bv, wqkv, wot, w1t, w2t, bqkv);
    inproj_kernel<<<dim3(MTOK), dim3(256), 0, stream>>>(x, Win, bin, h, h16);

    for (int l = 0; l < NLAYER; ++l) {
        // QKV: [16384,256]bf16 @ [256,768] -> bf16 qkv
        gemm_kernel<0, 0, 1><<<dim3(128, 6), dim3(256), 0, stream>>>(
            h16, wqkv + (size_t)l * 768 * 256, bqkv + l * 768, nullptr,
            qkv, MTOK, 768, 256);
        // flash attention
        attn_kernel<<<dim3(1024), dim3(512), 0, stream>>>(qkv, mask, ao);
        // Wo + residual: rbuf = h + ao@Wo + bo   (fp32 out)
        gemm_kernel<0, 1, 0><<<dim3(128, 2), dim3(256), 0, stream>>>(
            ao, wot + (size_t)l * 65536, bo + l * 256, h, rbuf, MTOK, 256, 256);
        // h = LN(rbuf), + bf16 copy
        ln_kernel<<<dim3(MTOK / 4), dim3(256), 0, stream>>>(
            rbuf, g1 + l * 256, b1 + l * 256, h, h16);
        // FF1: relu(h@W1 + c1) -> bf16 ffT
        gemm_kernel<1, 0, 1><<<dim3(128, 8), dim3(256), 0, stream>>>(
            h16, w1t + (size_t)l * 262144, c1 + l * 1024, nullptr,
            ffT, MTOK, 1024, 256);
        // FF2 + residual: rbuf = h + ffT@W2 + c2  (fp32 out)
        gemm_kernel<0, 1, 0><<<dim3(128, 2), dim3(256), 0, stream>>>(
            ffT, w2t + (size_t)l * 262144, c2 + l * 256, h, rbuf, MTOK, 256, 1024);
        // h = LN(rbuf)  (last layer writes d_out, no bf16 copy needed)
        ln_kernel<<<dim3(MTOK / 4), dim3(256), 0, stream>>>(
            rbuf, g2 + l * 256, b2 + l * 256,
            (l == 2) ? (float*)d_out : h, (l == 2) ? nullptr : h16);
    }
}

// Round 4
// 397.076 us; speedup vs baseline: 3.1435x; 1.1221x over previous
//
#include <hip/hip_runtime.h>
#include <cstdint>

#define NLAYER 3
#define DMODEL 256
#define NHEAD 8
#define HEADD 32
#define FFDIM 1024
#define BATCH 32
#define SEQ 512
#define MTOK (BATCH*SEQ)   // 16384

typedef __attribute__((ext_vector_type(8))) __bf16 bf16x8;
typedef __attribute__((ext_vector_type(4))) __bf16 bf16x4;
typedef __attribute__((ext_vector_type(4))) float f32x4;
typedef __attribute__((ext_vector_type(16))) float f32x16;

typedef __attribute__((address_space(1))) const uint8_t ga_t;
typedef __attribute__((address_space(3))) uint8_t la_t;
__device__ __forceinline__ void gll16(const void* g, void* l) {
    __builtin_amdgcn_global_load_lds((ga_t*)g, (la_t*)l, 16, 0, 0);
}

// ---------------------------------------------------------------------------
// Weight prep: fp32 [K][N] -> bf16 [N][K] (transposed), plus QKV bias concat.
// ---------------------------------------------------------------------------
__global__ __launch_bounds__(256)
void prep_kernel(const float* __restrict__ Wq, const float* __restrict__ Wk,
                 const float* __restrict__ Wv, const float* __restrict__ Wo,
                 const float* __restrict__ W1, const float* __restrict__ W2,
                 const float* __restrict__ bq, const float* __restrict__ bk,
                 const float* __restrict__ bv,
                 __bf16* __restrict__ wqkv, __bf16* __restrict__ wot,
                 __bf16* __restrict__ w1t, __bf16* __restrict__ w2t,
                 float* __restrict__ bqkv)
{
    const int bid = blockIdx.x;
    const int tid = threadIdx.x;
    if (bid >= 3 * 768) {
        int idx = (bid - 3 * 768) * 256 + tid;  // 0..2303
        int l = idx / 768, j = idx % 768;
        float v = (j < 256) ? bq[l * 256 + j]
                : (j < 512) ? bk[l * 256 + j - 256]
                            : bv[l * 256 + j - 512];
        bqkv[idx] = v;
        return;
    }
    const int l = bid / 768;
    const int rr = bid % 768;
    const float* src; __bf16* dst; int K, N, t;
    if (rr < 192) {
        int ty = rr >> 6; t = rr & 63;
        src = (ty == 0 ? Wq : ty == 1 ? Wk : Wv) + (size_t)l * 65536;
        dst = wqkv + (size_t)l * 768 * 256 + (size_t)ty * 65536;
        K = 256; N = 256;
    } else if (rr < 256) {
        t = rr - 192; src = Wo + (size_t)l * 65536; dst = wot + (size_t)l * 65536;
        K = 256; N = 256;
    } else if (rr < 512) {
        t = rr - 256; src = W1 + (size_t)l * 262144; dst = w1t + (size_t)l * 262144;
        K = 256; N = 1024;
    } else {
        t = rr - 512; src = W2 + (size_t)l * 262144; dst = w2t + (size_t)l * 262144;
        K = 1024; N = 256;
    }
    const int tn = N >> 5;
    const int tk = t / tn, tj = t % tn;
    __shared__ float tile[32][33];
    const int c = tid & 31, rbase = tid >> 5;  // rbase 0..7
#pragma unroll
    for (int p = 0; p < 4; ++p) {
        int kr = rbase + p * 8;
        tile[kr][c] = src[(size_t)(tk * 32 + kr) * N + tj * 32 + c];
    }
    __syncthreads();
#pragma unroll
    for (int p = 0; p < 4; ++p) {
        int nr = rbase + p * 8;
        dst[(size_t)(tj * 32 + nr) * K + tk * 32 + c] = (__bf16)tile[c][nr];
    }
}

// ---------------------------------------------------------------------------
// Input projection: h = x@Win + bin, writes fp32 and bf16 copies.
// ---------------------------------------------------------------------------
__global__ __launch_bounds__(256)
void inproj_kernel(const float* __restrict__ x, const float* __restrict__ Win,
                   const float* __restrict__ bin, float* __restrict__ h,
                   __bf16* __restrict__ h16)
{
    const int m = blockIdx.x;
    const int n = threadIdx.x;
    const float* xr = x + (size_t)m * 5;
    float acc = bin[n];
#pragma unroll
    for (int k = 0; k < 5; ++k) acc += xr[k] * Win[k * DMODEL + n];
    h[(size_t)m * DMODEL + n] = acc;
    h16[(size_t)m * DMODEL + n] = (__bf16)acc;
}

// ---------------------------------------------------------------------------
// MFMA bf16 GEMM with global_load_lds staging + XOR chunk swizzle.
// 128x128 tile, BK=64, 256 threads (4 waves, 2x2 of 64x64).
// ---------------------------------------------------------------------------
template<int RELU, int RES, int OBF>
__global__ __launch_bounds__(256, 3)
void gemm_kernel(const __bf16* __restrict__ A, const __bf16* __restrict__ Bt,
                 const float* __restrict__ bias, const float* __restrict__ res,
                 void* __restrict__ Cv, int M, int N, int K)
{
    __shared__ __bf16 As[128 * 64];
    __shared__ __bf16 Bs[128 * 64];
    const int tid = threadIdx.x;
    const int m0 = blockIdx.x * 128;
    const int n0 = blockIdx.y * 128;
    const int lane = tid & 63;
    const int wave = tid >> 6;
    const int wm = (wave & 1) * 64;
    const int wn = (wave >> 1) * 64;
    const int fr = lane & 15;
    const int quad = lane >> 4;
    const int lr = lane >> 3;             // row-within-8 for staging
    const int qg = (lane & 7) ^ lr;       // swizzled source chunk

    const __bf16* Ab = A  + (size_t)(m0 + wave * 32 + lr) * K + qg * 8;
    const __bf16* Bb = Bt + (size_t)(n0 + wave * 32 + lr) * K + qg * 8;

    f32x4 acc[4][4];
#pragma unroll
    for (int i = 0; i < 4; ++i)
#pragma unroll
        for (int j = 0; j < 4; ++j)
#pragma unroll
            for (int r = 0; r < 4; ++r) acc[i][j][r] = 0.f;

    const int frs = fr & 7;

    for (int k0 = 0; k0 < K; k0 += 64) {
#pragma unroll
        for (int j = 0; j < 4; ++j) {
            gll16(Ab + (size_t)j * 8 * K + k0, As + (wave * 4 + j) * 512);
            gll16(Bb + (size_t)j * 8 * K + k0, Bs + (wave * 4 + j) * 512);
        }
        __syncthreads();
#pragma unroll
        for (int kk = 0; kk < 2; ++kk) {
            bf16x8 af[4], bfr[4];
#pragma unroll
            for (int i = 0; i < 4; ++i) {
                int row = wm + i * 16 + fr;
                af[i] = *(const bf16x8*)(As + row * 64 + (((kk * 4 + quad) ^ frs) * 8));
            }
#pragma unroll
            for (int j = 0; j < 4; ++j) {
                int row = wn + j * 16 + fr;
                bfr[j] = *(const bf16x8*)(Bs + row * 64 + (((kk * 4 + quad) ^ frs) * 8));
            }
#pragma unroll
            for (int i = 0; i < 4; ++i)
#pragma unroll
                for (int j = 0; j < 4; ++j)
                    acc[i][j] = __builtin_amdgcn_mfma_f32_16x16x32_bf16(
                        af[i], bfr[j], acc[i][j], 0, 0, 0);
        }
        __syncthreads();
    }

#pragma unroll
    for (int i = 0; i < 4; ++i) {
#pragma unroll
        for (int j = 0; j < 4; ++j) {
            const int gc = n0 + wn + j * 16 + fr;
            const float bv = bias[gc];
#pragma unroll
            for (int r = 0; r < 4; ++r) {
                const int gr = m0 + wm + i * 16 + quad * 4 + r;
                float v = acc[i][j][r] + bv;
                if (RES) v += res[(size_t)gr * N + gc];
                if (RELU) v = fmaxf(v, 0.f);
                if (OBF) ((__bf16*)Cv)[(size_t)gr * N + gc] = (__bf16)v;
                else     ((float*)Cv)[(size_t)gr * N + gc] = v;
            }
        }
    }
}

// ---------------------------------------------------------------------------
// MFMA flash attention, 32x32 tiles. One block per (b,h): grid=256, 1024 thr
// = 16 waves, each wave owns 32 queries. K/V staged once per (b,h).
// S^T = K.Q^T via 2x mfma_32x32x16 (dims 0-15, 16-31), D: col=lane&31=query,
// row=(reg&3)+8*(reg>>2)+4*(lane>>5)=key  [m74/m101 verified].
// No online max (scores provably tiny: |s*scale| << 1): p=exp(s), l summed
// per-lane, one shfl_xor(32) at the end. O^T = V^T.P^T (col=query).
// LDS strides: Ks 40 (80B), Vt 520 (1040B), Pw 40 -> all b128-aligned.
// ---------------------------------------------------------------------------
__global__ __launch_bounds__(1024)
void attn_kernel(const __bf16* __restrict__ qkv, const int* __restrict__ mask,
                 __bf16* __restrict__ ao)
{
    __shared__ __bf16 Ks[512 * 40];      // 40960 B
    __shared__ __bf16 Vt[32 * 520];      // 33280 B
    __shared__ __bf16 Pq[16 * 32 * 40];  // 40960 B
    __shared__ float maskadd[512];       //  2048 B

    const int b = blockIdx.x >> 3;
    const int h = blockIdx.x & 7;
    const int t = threadIdx.x;
    const int lane = t & 63;
    const int wave = t >> 6;             // 0..15
    const int cl = lane & 31;            // query-within-tile / A-row
    const int kh = lane >> 5;            // k-half selector
    const float scale = 0.17677669529663687f;  // 1/sqrt(32)

    const size_t base = (size_t)b * SEQ * 768;

    // ---- stage K rows and V transposed (once per (b,h)) ----
#pragma unroll
    for (int p = 0; p < 2; ++p) {
        int idx = p * 1024 + t;          // 0..2047
        int key = idx >> 2, ch = idx & 3;
        bf16x8 kv = *(const bf16x8*)(qkv + base + (size_t)key * 768 + 256 + h * 32 + ch * 8);
        *(bf16x8*)(Ks + key * 40 + ch * 8) = kv;
        bf16x8 vv = *(const bf16x8*)(qkv + base + (size_t)key * 768 + 512 + h * 32 + ch * 8);
#pragma unroll
        for (int j = 0; j < 8; ++j) Vt[(ch * 8 + j) * 520 + key] = vv[j];
    }
    if (t < 512) maskadd[t] = mask[b * SEQ + t] ? -1e30f : 0.f;
    __syncthreads();

    // ---- Q fragments (B-operand: n=query=cl, k=dim) ----
    const int q0 = wave * 32;
    const __bf16* qrow = qkv + base + (size_t)(q0 + cl) * 768 + h * 32;
    bf16x8 qf0 = *(const bf16x8*)(qrow + kh * 8);        // dims 0..15
    bf16x8 qf1 = *(const bf16x8*)(qrow + 16 + kh * 8);   // dims 16..31

    f32x16 oacc;
#pragma unroll
    for (int i = 0; i < 16; ++i) oacc[i] = 0.f;
    float lsum = 0.f;
    __bf16* Pw = Pq + wave * 32 * 40;

    for (int kt = 0; kt < SEQ; kt += 32) {
        // K A-frags (m=key=cl within tile, k=dim halves)
        bf16x8 kf0 = *(const bf16x8*)(Ks + (kt + cl) * 40 + kh * 8);
        bf16x8 kf1 = *(const bf16x8*)(Ks + (kt + cl) * 40 + 16 + kh * 8);
        f32x16 s;
#pragma unroll
        for (int i = 0; i < 16; ++i) s[i] = 0.f;
        s = __builtin_amdgcn_mfma_f32_32x32x16_bf16(kf0, qf0, s, 0, 0, 0);
        s = __builtin_amdgcn_mfma_f32_32x32x16_bf16(kf1, qf1, s, 0, 0, 0);
        // softmax numerator (fixed max = 0), pack P^T per reg-group
        float pv[16];
#pragma unroll
        for (int g = 0; g < 4; ++g) {
            f32x4 mv = *(const f32x4*)(maskadd + kt + 8 * g + 4 * kh);
#pragma unroll
            for (int r = 0; r < 4; ++r) {
                float e = __expf(s[g * 4 + r] * scale + mv[r]);
                pv[g * 4 + r] = e;
                lsum += e;
            }
        }
#pragma unroll
        for (int g = 0; g < 4; ++g) {
            bf16x4 pb;
#pragma unroll
            for (int r = 0; r < 4; ++r) pb[r] = (__bf16)pv[g * 4 + r];
            *(bf16x4*)(Pw + cl * 40 + 8 * g + 4 * kh) = pb;   // P^T[q][key]
        }
        // B-frags of P^T (n=query=cl, k=key halves) — per-wave, no barrier
        bf16x8 pf0 = *(const bf16x8*)(Pw + cl * 40 + kh * 8);
        bf16x8 pf1 = *(const bf16x8*)(Pw + cl * 40 + 16 + kh * 8);
        // V^T A-frags (m=d=cl, k=key halves)
        bf16x8 vf0 = *(const bf16x8*)(Vt + cl * 520 + kt + kh * 8);
        bf16x8 vf1 = *(const bf16x8*)(Vt + cl * 520 + kt + 16 + kh * 8);
        oacc = __builtin_amdgcn_mfma_f32_32x32x16_bf16(vf0, pf0, oacc, 0, 0, 0);
        oacc = __builtin_amdgcn_mfma_f32_32x32x16_bf16(vf1, pf1, oacc, 0, 0, 0);
    }

    lsum += __shfl_xor(lsum, 32);
    const float inv = (lsum > 0.f) ? 1.f / lsum : 0.f;
    // O^T: lane holds O[q=cl][d = 8g + 4*kh + r]
    __bf16* orow = ao + (size_t)(b * SEQ + q0 + cl) * DMODEL + h * 32;
#pragma unroll
    for (int g = 0; g < 4; ++g) {
        bf16x4 w;
#pragma unroll
        for (int r = 0; r < 4; ++r) w[r] = (__bf16)(oacc[g * 4 + r] * inv);
        *(bf16x4*)(orow + 8 * g + 4 * kh) = w;
    }
}

// ---------------------------------------------------------------------------
// LayerNorm over 256: one wave per row; writes fp32 and optional bf16 copy.
// ---------------------------------------------------------------------------
__global__ __launch_bounds__(256)
void ln_kernel(const float* __restrict__ rin, const float* __restrict__ g,
               const float* __restrict__ be, float* __restrict__ out,
               __bf16* __restrict__ out16)
{
    const int row = blockIdx.x * 4 + (threadIdx.x >> 6);
    const int lane = threadIdx.x & 63;
    const float* x = rin + (size_t)row * DMODEL + lane * 4;
    f32x4 v = *(const f32x4*)x;
    float s = v[0] + v[1] + v[2] + v[3];
    float ss = v[0] * v[0] + v[1] * v[1] + v[2] * v[2] + v[3] * v[3];
#pragma unroll
    for (int off = 1; off < 64; off <<= 1) {
        s  += __shfl_xor(s, off, 64);
        ss += __shfl_xor(ss, off, 64);
    }
    const float mu = s * (1.f / DMODEL);
    const float var = ss * (1.f / DMODEL) - mu * mu;
    const float rs = rsqrtf(var + 1e-5f);
    f32x4 gv = *(const f32x4*)(g + lane * 4);
    f32x4 bv = *(const f32x4*)(be + lane * 4);
    f32x4 y;
#pragma unroll
    for (int i = 0; i < 4; ++i) y[i] = (v[i] - mu) * rs * gv[i] + bv[i];
    *(f32x4*)(out + (size_t)row * DMODEL + lane * 4) = y;
    if (out16) {
        bf16x4 yb;
#pragma unroll
        for (int i = 0; i < 4; ++i) yb[i] = (__bf16)y[i];
        *(bf16x4*)(out16 + (size_t)row * DMODEL + lane * 4) = yb;
    }
}

// ---------------------------------------------------------------------------
extern "C" void kernel_launch(void* const* d_in, const int* in_sizes, int n_in,
                              void* d_out, int out_size, void* d_ws, size_t ws_size,
                              hipStream_t stream)
{
    const float* x   = (const float*)d_in[0];
    const int*   mask= (const int*)d_in[1];
    const float* Win = (const float*)d_in[2];
    const float* bin = (const float*)d_in[3];
    const float* Wq  = (const float*)d_in[4];
    const float* bq  = (const float*)d_in[5];
    const float* Wk  = (const float*)d_in[6];
    const float* bk  = (const float*)d_in[7];
    const float* Wv  = (const float*)d_in[8];
    const float* bv  = (const float*)d_in[9];
    const float* Wo  = (const float*)d_in[10];
    const float* bo  = (const float*)d_in[11];
    const float* g1  = (const float*)d_in[12];
    const float* b1  = (const float*)d_in[13];
    const float* W1  = (const float*)d_in[14];
    const float* c1  = (const float*)d_in[15];
    const float* W2  = (const float*)d_in[16];
    const float* c2  = (const float*)d_in[17];
    const float* g2  = (const float*)d_in[18];
    const float* b2  = (const float*)d_in[19];

    char* ws = (char*)d_ws;
    size_t off = 0;
    auto alloc = [&](size_t bytes) -> void* {
        void* p = ws + off;
        off += (bytes + 255) & ~(size_t)255;
        return p;
    };
    float*  h    = (float*)alloc((size_t)MTOK * 256 * 4);   // 16 MB
    __bf16* h16  = (__bf16*)alloc((size_t)MTOK * 256 * 2);  // 8 MB
    float*  rbuf = (float*)alloc((size_t)MTOK * 256 * 4);   // 16 MB
    __bf16* u    = (__bf16*)alloc((size_t)MTOK * 1024 * 2); // 32 MB (qkv / ff union)
    __bf16* qkv  = u;
    __bf16* ffT  = u;
    __bf16* ao   = (__bf16*)alloc((size_t)MTOK * 256 * 2);  // 8 MB
    __bf16* wqkv = (__bf16*)alloc((size_t)3 * 768 * 256 * 2);
    __bf16* wot  = (__bf16*)alloc((size_t)3 * 256 * 256 * 2);
    __bf16* w1t  = (__bf16*)alloc((size_t)3 * 1024 * 256 * 2);
    __bf16* w2t  = (__bf16*)alloc((size_t)3 * 256 * 1024 * 2);
    float*  bqkv = (float*)alloc((size_t)3 * 768 * 4);

    prep_kernel<<<dim3(2313), dim3(256), 0, stream>>>(
        Wq, Wk, Wv, Wo, W1, W2, bq, bk, bv, wqkv, wot, w1t, w2t, bqkv);
    inproj_kernel<<<dim3(MTOK), dim3(256), 0, stream>>>(x, Win, bin, h, h16);

    for (int l = 0; l < NLAYER; ++l) {
        // QKV: [16384,256]bf16 @ [256,768] -> bf16 qkv
        gemm_kernel<0, 0, 1><<<dim3(128, 6), dim3(256), 0, stream>>>(
            h16, wqkv + (size_t)l * 768 * 256, bqkv + l * 768, nullptr,
            qkv, MTOK, 768, 256);
        // flash attention (one block per (b,h))
        attn_kernel<<<dim3(256), dim3(1024), 0, stream>>>(qkv, mask, ao);
        // Wo + residual: rbuf = h + ao@Wo + bo   (fp32 out)
        gemm_kernel<0, 1, 0><<<dim3(128, 2), dim3(256), 0, stream>>>(
            ao, wot + (size_t)l * 65536, bo + l * 256, h, rbuf, MTOK, 256, 256);
        // h = LN(rbuf), + bf16 copy
        ln_kernel<<<dim3(MTOK / 4), dim3(256), 0, stream>>>(
            rbuf, g1 + l * 256, b1 + l * 256, h, h16);
        // FF1: relu(h@W1 + c1) -> bf16 ffT
        gemm_kernel<1, 0, 1><<<dim3(128, 8), dim3(256), 0, stream>>>(
            h16, w1t + (size_t)l * 262144, c1 + l * 1024, nullptr,
            ffT, MTOK, 1024, 256);
        // FF2 + residual: rbuf = h + ffT@W2 + c2  (fp32 out)
        gemm_kernel<0, 1, 0><<<dim3(128, 2), dim3(256), 0, stream>>>(
            ffT, w2t + (size_t)l * 262144, c2 + l * 256, h, rbuf, MTOK, 256, 1024);
        // h = LN(rbuf)  (last layer writes d_out, no bf16 copy needed)
        ln_kernel<<<dim3(MTOK / 4), dim3(256), 0, stream>>>(
            rbuf, g2 + l * 256, b2 + l * 256,
            (l == 2) ? (float*)d_out : h, (l == 2) ? nullptr : h16);
    }
}

// Round 5
// 392.025 us; speedup vs baseline: 3.1840x; 1.0129x over previous
//
#include <hip/hip_runtime.h>
#include <cstdint>

#define NLAYER 3
#define DMODEL 256
#define NHEAD 8
#define HEADD 32
#define FFDIM 1024
#define BATCH 32
#define SEQ 512
#define MTOK (BATCH*SEQ)   // 16384

typedef __attribute__((ext_vector_type(8))) __bf16 bf16x8;
typedef __attribute__((ext_vector_type(4))) __bf16 bf16x4;
typedef __attribute__((ext_vector_type(4))) float f32x4;
typedef __attribute__((ext_vector_type(16))) float f32x16;

typedef __attribute__((address_space(1))) const uint8_t ga_t;
typedef __attribute__((address_space(3))) uint8_t la_t;
__device__ __forceinline__ void gll16(const void* g, void* l) {
    __builtin_amdgcn_global_load_lds((ga_t*)g, (la_t*)l, 16, 0, 0);
}

// ---------------------------------------------------------------------------
// Weight prep: fp32 [K][N] -> bf16 [N][K] (transposed), plus QKV bias concat.
// ---------------------------------------------------------------------------
__global__ __launch_bounds__(256)
void prep_kernel(const float* __restrict__ Wq, const float* __restrict__ Wk,
                 const float* __restrict__ Wv, const float* __restrict__ Wo,
                 const float* __restrict__ W1, const float* __restrict__ W2,
                 const float* __restrict__ bq, const float* __restrict__ bk,
                 const float* __restrict__ bv,
                 __bf16* __restrict__ wqkv, __bf16* __restrict__ wot,
                 __bf16* __restrict__ w1t, __bf16* __restrict__ w2t,
                 float* __restrict__ bqkv)
{
    const int bid = blockIdx.x;
    const int tid = threadIdx.x;
    if (bid >= 3 * 768) {
        int idx = (bid - 3 * 768) * 256 + tid;  // 0..2303
        int l = idx / 768, j = idx % 768;
        float v = (j < 256) ? bq[l * 256 + j]
                : (j < 512) ? bk[l * 256 + j - 256]
                            : bv[l * 256 + j - 512];
        bqkv[idx] = v;
        return;
    }
    const int l = bid / 768;
    const int rr = bid % 768;
    const float* src; __bf16* dst; int K, N, t;
    if (rr < 192) {
        int ty = rr >> 6; t = rr & 63;
        src = (ty == 0 ? Wq : ty == 1 ? Wk : Wv) + (size_t)l * 65536;
        dst = wqkv + (size_t)l * 768 * 256 + (size_t)ty * 65536;
        K = 256; N = 256;
    } else if (rr < 256) {
        t = rr - 192; src = Wo + (size_t)l * 65536; dst = wot + (size_t)l * 65536;
        K = 256; N = 256;
    } else if (rr < 512) {
        t = rr - 256; src = W1 + (size_t)l * 262144; dst = w1t + (size_t)l * 262144;
        K = 256; N = 1024;
    } else {
        t = rr - 512; src = W2 + (size_t)l * 262144; dst = w2t + (size_t)l * 262144;
        K = 1024; N = 256;
    }
    const int tn = N >> 5;
    const int tk = t / tn, tj = t % tn;
    __shared__ float tile[32][33];
    const int c = tid & 31, rbase = tid >> 5;  // rbase 0..7
#pragma unroll
    for (int p = 0; p < 4; ++p) {
        int kr = rbase + p * 8;
        tile[kr][c] = src[(size_t)(tk * 32 + kr) * N + tj * 32 + c];
    }
    __syncthreads();
#pragma unroll
    for (int p = 0; p < 4; ++p) {
        int nr = rbase + p * 8;
        dst[(size_t)(tj * 32 + nr) * K + tk * 32 + c] = (__bf16)tile[c][nr];
    }
}

// ---------------------------------------------------------------------------
// Input projection: h16 = bf16(x@Win + bin)
// ---------------------------------------------------------------------------
__global__ __launch_bounds__(256)
void inproj_kernel(const float* __restrict__ x, const float* __restrict__ Win,
                   const float* __restrict__ bin, __bf16* __restrict__ h16)
{
    const int m = blockIdx.x;
    const int n = threadIdx.x;
    const float* xr = x + (size_t)m * 5;
    float acc = bin[n];
#pragma unroll
    for (int k = 0; k < 5; ++k) acc += xr[k] * Win[k * DMODEL + n];
    h16[(size_t)m * DMODEL + n] = (__bf16)acc;
}

// ---------------------------------------------------------------------------
// MFMA bf16 GEMM with global_load_lds staging + XOR chunk swizzle.
// 128x128 tile, BK=64, 256 threads (4 waves, 2x2 of 64x64). bf16 out.
// Used for QKV (N=768) and FF1 (N=1024, RELU).
// ---------------------------------------------------------------------------
template<int RELU>
__global__ __launch_bounds__(256, 3)
void gemm_kernel(const __bf16* __restrict__ A, const __bf16* __restrict__ Bt,
                 const float* __restrict__ bias,
                 __bf16* __restrict__ C, int M, int N, int K)
{
    __shared__ __bf16 As[128 * 64];
    __shared__ __bf16 Bs[128 * 64];
    const int tid = threadIdx.x;
    const int m0 = blockIdx.x * 128;
    const int n0 = blockIdx.y * 128;
    const int lane = tid & 63;
    const int wave = tid >> 6;
    const int wm = (wave & 1) * 64;
    const int wn = (wave >> 1) * 64;
    const int fr = lane & 15;
    const int quad = lane >> 4;
    const int lr = lane >> 3;             // row-within-8 for staging
    const int qg = (lane & 7) ^ lr;       // swizzled source chunk

    const __bf16* Ab = A  + (size_t)(m0 + wave * 32 + lr) * K + qg * 8;
    const __bf16* Bb = Bt + (size_t)(n0 + wave * 32 + lr) * K + qg * 8;

    f32x4 acc[4][4];
#pragma unroll
    for (int i = 0; i < 4; ++i)
#pragma unroll
        for (int j = 0; j < 4; ++j)
#pragma unroll
            for (int r = 0; r < 4; ++r) acc[i][j][r] = 0.f;

    const int frs = fr & 7;

    for (int k0 = 0; k0 < K; k0 += 64) {
#pragma unroll
        for (int j = 0; j < 4; ++j) {
            gll16(Ab + (size_t)j * 8 * K + k0, As + (wave * 4 + j) * 512);
            gll16(Bb + (size_t)j * 8 * K + k0, Bs + (wave * 4 + j) * 512);
        }
        __syncthreads();
#pragma unroll
        for (int kk = 0; kk < 2; ++kk) {
            bf16x8 af[4], bfr[4];
#pragma unroll
            for (int i = 0; i < 4; ++i) {
                int row = wm + i * 16 + fr;
                af[i] = *(const bf16x8*)(As + row * 64 + (((kk * 4 + quad) ^ frs) * 8));
            }
#pragma unroll
            for (int j = 0; j < 4; ++j) {
                int row = wn + j * 16 + fr;
                bfr[j] = *(const bf16x8*)(Bs + row * 64 + (((kk * 4 + quad) ^ frs) * 8));
            }
#pragma unroll
            for (int i = 0; i < 4; ++i)
#pragma unroll
                for (int j = 0; j < 4; ++j)
                    acc[i][j] = __builtin_amdgcn_mfma_f32_16x16x32_bf16(
                        af[i], bfr[j], acc[i][j], 0, 0, 0);
        }
        __syncthreads();
    }

#pragma unroll
    for (int i = 0; i < 4; ++i) {
#pragma unroll
        for (int j = 0; j < 4; ++j) {
            const int gc = n0 + wn + j * 16 + fr;
            const float bv = bias[gc];
#pragma unroll
            for (int r = 0; r < 4; ++r) {
                const int gr = m0 + wm + i * 16 + quad * 4 + r;
                float v = acc[i][j][r] + bv;
                if (RELU) v = fmaxf(v, 0.f);
                C[(size_t)gr * N + gc] = (__bf16)v;
            }
        }
    }
}

// ---------------------------------------------------------------------------
// Fused GEMM + residual + LayerNorm, N=256 (whole rows per block).
// 64x256 tile, 256 threads = 4 waves (each 64x64, wn=wave*64), grid M/64.
// Epilogue: v = acc + bias + res(bf16); per-row mean/var via shfl_xor over
// fr (16 lanes) + cross-wave LDS exchange red[64][4]; y=(v-mu)*rs*g+b.
// LAST=0: write bf16 out16. LAST=1: write fp32 out32 (d_out).
// ---------------------------------------------------------------------------
template<int LAST>
__global__ __launch_bounds__(256, 2)
void gemm_ln_kernel(const __bf16* __restrict__ A, const __bf16* __restrict__ Bt,
                    const float* __restrict__ bias, const __bf16* __restrict__ res,
                    const float* __restrict__ g, const float* __restrict__ be,
                    __bf16* __restrict__ out16, float* __restrict__ out32, int K)
{
    __shared__ __bf16 As[64 * 64];    //  8 KB
    __shared__ __bf16 Bs[256 * 64];   // 32 KB
    __shared__ float red[64 * 8];     //  2 KB  (row -> 4x {sum, sumsq})
    const int tid = threadIdx.x;
    const int m0 = blockIdx.x * 64;
    const int lane = tid & 63;
    const int wave = tid >> 6;            // 0..3
    const int wn = wave * 64;
    const int fr = lane & 15;
    const int quad = lane >> 4;
    const int lr = lane >> 3;
    const int qg = (lane & 7) ^ lr;
    const int frs = fr & 7;

    const __bf16* Ab = A  + (size_t)(m0 + wave * 16 + lr) * K + qg * 8;
    const __bf16* Bb = Bt + (size_t)(wave * 64 + lr) * K + qg * 8;

    f32x4 acc[4][4];
#pragma unroll
    for (int i = 0; i < 4; ++i)
#pragma unroll
        for (int j = 0; j < 4; ++j)
#pragma unroll
            for (int r = 0; r < 4; ++r) acc[i][j][r] = 0.f;

    for (int k0 = 0; k0 < K; k0 += 64) {
#pragma unroll
        for (int p = 0; p < 2; ++p)
            gll16(Ab + (size_t)p * 8 * K + k0, As + (wave * 2 + p) * 512);
#pragma unroll
        for (int p = 0; p < 8; ++p)
            gll16(Bb + (size_t)p * 8 * K + k0, Bs + (wave * 8 + p) * 512);
        __syncthreads();
#pragma unroll
        for (int kk = 0; kk < 2; ++kk) {
            bf16x8 af[4], bfr[4];
#pragma unroll
            for (int i = 0; i < 4; ++i) {
                int row = i * 16 + fr;
                af[i] = *(const bf16x8*)(As + row * 64 + (((kk * 4 + quad) ^ frs) * 8));
            }
#pragma unroll
            for (int j = 0; j < 4; ++j) {
                int row = wn + j * 16 + fr;
                bfr[j] = *(const bf16x8*)(Bs + row * 64 + (((kk * 4 + quad) ^ frs) * 8));
            }
#pragma unroll
            for (int i = 0; i < 4; ++i)
#pragma unroll
                for (int j = 0; j < 4; ++j)
                    acc[i][j] = __builtin_amdgcn_mfma_f32_16x16x32_bf16(
                        af[i], bfr[j], acc[i][j], 0, 0, 0);
        }
        __syncthreads();
    }

    // ---- epilogue: v = acc + bias + res; per-row LN over 256 cols ----
    float bv[4];
#pragma unroll
    for (int j = 0; j < 4; ++j) bv[j] = bias[wn + j * 16 + fr];

#pragma unroll
    for (int i = 0; i < 4; ++i) {
#pragma unroll
        for (int r = 0; r < 4; ++r) {
            const int row = i * 16 + quad * 4 + r;     // 0..63
            float ps = 0.f, pq = 0.f;
#pragma unroll
            for (int j = 0; j < 4; ++j) {
                const int gc = wn + j * 16 + fr;
                float v = acc[i][j][r] + bv[j]
                        + (float)res[(size_t)(m0 + row) * DMODEL + gc];
                acc[i][j][r] = v;
                ps += v;
                pq += v * v;
            }
#pragma unroll
            for (int off = 1; off < 16; off <<= 1) {
                ps += __shfl_xor(ps, off, 64);
                pq += __shfl_xor(pq, off, 64);
            }
            if (fr == 0) {
                red[row * 8 + wave * 2]     = ps;
                red[row * 8 + wave * 2 + 1] = pq;
            }
        }
    }
    __syncthreads();

#pragma unroll
    for (int i = 0; i < 4; ++i) {
#pragma unroll
        for (int r = 0; r < 4; ++r) {
            const int row = i * 16 + quad * 4 + r;
            f32x4 a = *(const f32x4*)(red + row * 8);
            f32x4 b2 = *(const f32x4*)(red + row * 8 + 4);
            const float s  = a[0] + a[2] + b2[0] + b2[2];
            const float sq = a[1] + a[3] + b2[1] + b2[3];
            const float mu = s * (1.f / DMODEL);
            const float var = sq * (1.f / DMODEL) - mu * mu;
            const float rs = rsqrtf(var + 1e-5f);
#pragma unroll
            for (int j = 0; j < 4; ++j) {
                const int gc = wn + j * 16 + fr;
                float y = (acc[i][j][r] - mu) * rs * g[gc] + be[gc];
                if (LAST) out32[(size_t)(m0 + row) * DMODEL + gc] = y;
                else      out16[(size_t)(m0 + row) * DMODEL + gc] = (__bf16)y;
            }
        }
    }
}

// ---------------------------------------------------------------------------
// MFMA flash attention, 32x32 tiles. One block per (b,h): grid=256, 1024 thr
// = 16 waves, each wave owns 32 queries. (unchanged from round 4)
// ---------------------------------------------------------------------------
__global__ __launch_bounds__(1024)
void attn_kernel(const __bf16* __restrict__ qkv, const int* __restrict__ mask,
                 __bf16* __restrict__ ao)
{
    __shared__ __bf16 Ks[512 * 40];      // 40960 B
    __shared__ __bf16 Vt[32 * 520];      // 33280 B
    __shared__ __bf16 Pq[16 * 32 * 40];  // 40960 B
    __shared__ float maskadd[512];       //  2048 B

    const int b = blockIdx.x >> 3;
    const int h = blockIdx.x & 7;
    const int t = threadIdx.x;
    const int lane = t & 63;
    const int wave = t >> 6;             // 0..15
    const int cl = lane & 31;
    const int kh = lane >> 5;
    const float scale = 0.17677669529663687f;  // 1/sqrt(32)

    const size_t base = (size_t)b * SEQ * 768;

#pragma unroll
    for (int p = 0; p < 2; ++p) {
        int idx = p * 1024 + t;          // 0..2047
        int key = idx >> 2, ch = idx & 3;
        bf16x8 kv = *(const bf16x8*)(qkv + base + (size_t)key * 768 + 256 + h * 32 + ch * 8);
        *(bf16x8*)(Ks + key * 40 + ch * 8) = kv;
        bf16x8 vv = *(const bf16x8*)(qkv + base + (size_t)key * 768 + 512 + h * 32 + ch * 8);
#pragma unroll
        for (int j = 0; j < 8; ++j) Vt[(ch * 8 + j) * 520 + key] = vv[j];
    }
    if (t < 512) maskadd[t] = mask[b * SEQ + t] ? -1e30f : 0.f;
    __syncthreads();

    const int q0 = wave * 32;
    const __bf16* qrow = qkv + base + (size_t)(q0 + cl) * 768 + h * 32;
    bf16x8 qf0 = *(const bf16x8*)(qrow + kh * 8);
    bf16x8 qf1 = *(const bf16x8*)(qrow + 16 + kh * 8);

    f32x16 oacc;
#pragma unroll
    for (int i = 0; i < 16; ++i) oacc[i] = 0.f;
    float lsum = 0.f;
    __bf16* Pw = Pq + wave * 32 * 40;

    for (int kt = 0; kt < SEQ; kt += 32) {
        bf16x8 kf0 = *(const bf16x8*)(Ks + (kt + cl) * 40 + kh * 8);
        bf16x8 kf1 = *(const bf16x8*)(Ks + (kt + cl) * 40 + 16 + kh * 8);
        f32x16 s;
#pragma unroll
        for (int i = 0; i < 16; ++i) s[i] = 0.f;
        s = __builtin_amdgcn_mfma_f32_32x32x16_bf16(kf0, qf0, s, 0, 0, 0);
        s = __builtin_amdgcn_mfma_f32_32x32x16_bf16(kf1, qf1, s, 0, 0, 0);
        float pv[16];
#pragma unroll
        for (int g = 0; g < 4; ++g) {
            f32x4 mv = *(const f32x4*)(maskadd + kt + 8 * g + 4 * kh);
#pragma unroll
            for (int r = 0; r < 4; ++r) {
                float e = __expf(s[g * 4 + r] * scale + mv[r]);
                pv[g * 4 + r] = e;
                lsum += e;
            }
        }
#pragma unroll
        for (int g = 0; g < 4; ++g) {
            bf16x4 pb;
#pragma unroll
            for (int r = 0; r < 4; ++r) pb[r] = (__bf16)pv[g * 4 + r];
            *(bf16x4*)(Pw + cl * 40 + 8 * g + 4 * kh) = pb;
        }
        bf16x8 pf0 = *(const bf16x8*)(Pw + cl * 40 + kh * 8);
        bf16x8 pf1 = *(const bf16x8*)(Pw + cl * 40 + 16 + kh * 8);
        bf16x8 vf0 = *(const bf16x8*)(Vt + cl * 520 + kt + kh * 8);
        bf16x8 vf1 = *(const bf16x8*)(Vt + cl * 520 + kt + 16 + kh * 8);
        oacc = __builtin_amdgcn_mfma_f32_32x32x16_bf16(vf0, pf0, oacc, 0, 0, 0);
        oacc = __builtin_amdgcn_mfma_f32_32x32x16_bf16(vf1, pf1, oacc, 0, 0, 0);
    }

    lsum += __shfl_xor(lsum, 32);
    const float inv = (lsum > 0.f) ? 1.f / lsum : 0.f;
    __bf16* orow = ao + (size_t)(b * SEQ + q0 + cl) * DMODEL + h * 32;
#pragma unroll
    for (int g = 0; g < 4; ++g) {
        bf16x4 w;
#pragma unroll
        for (int r = 0; r < 4; ++r) w[r] = (__bf16)(oacc[g * 4 + r] * inv);
        *(bf16x4*)(orow + 8 * g + 4 * kh) = w;
    }
}

// ---------------------------------------------------------------------------
extern "C" void kernel_launch(void* const* d_in, const int* in_sizes, int n_in,
                              void* d_out, int out_size, void* d_ws, size_t ws_size,
                              hipStream_t stream)
{
    const float* x   = (const float*)d_in[0];
    const int*   mask= (const int*)d_in[1];
    const float* Win = (const float*)d_in[2];
    const float* bin = (const float*)d_in[3];
    const float* Wq  = (const float*)d_in[4];
    const float* bq  = (const float*)d_in[5];
    const float* Wk  = (const float*)d_in[6];
    const float* bk  = (const float*)d_in[7];
    const float* Wv  = (const float*)d_in[8];
    const float* bv  = (const float*)d_in[9];
    const float* Wo  = (const float*)d_in[10];
    const float* bo  = (const float*)d_in[11];
    const float* g1  = (const float*)d_in[12];
    const float* b1  = (const float*)d_in[13];
    const float* W1  = (const float*)d_in[14];
    const float* c1  = (const float*)d_in[15];
    const float* W2  = (const float*)d_in[16];
    const float* c2  = (const float*)d_in[17];
    const float* g2  = (const float*)d_in[18];
    const float* b2  = (const float*)d_in[19];

    char* ws = (char*)d_ws;
    size_t off = 0;
    auto alloc = [&](size_t bytes) -> void* {
        void* p = ws + off;
        off += (bytes + 255) & ~(size_t)255;
        return p;
    };
    __bf16* hA   = (__bf16*)alloc((size_t)MTOK * 256 * 2);  // 8 MB (residual s_l)
    __bf16* hB   = (__bf16*)alloc((size_t)MTOK * 256 * 2);  // 8 MB (LN1 out t_l)
    __bf16* u    = (__bf16*)alloc((size_t)MTOK * 1024 * 2); // 32 MB (qkv / ff union)
    __bf16* qkv  = u;
    __bf16* ffT  = u;
    __bf16* ao   = (__bf16*)alloc((size_t)MTOK * 256 * 2);  // 8 MB
    __bf16* wqkv = (__bf16*)alloc((size_t)3 * 768 * 256 * 2);
    __bf16* wot  = (__bf16*)alloc((size_t)3 * 256 * 256 * 2);
    __bf16* w1t  = (__bf16*)alloc((size_t)3 * 1024 * 256 * 2);
    __bf16* w2t  = (__bf16*)alloc((size_t)3 * 256 * 1024 * 2);
    float*  bqkv = (float*)alloc((size_t)3 * 768 * 4);

    prep_kernel<<<dim3(2313), dim3(256), 0, stream>>>(
        Wq, Wk, Wv, Wo, W1, W2, bq, bk, bv, wqkv, wot, w1t, w2t, bqkv);
    inproj_kernel<<<dim3(MTOK), dim3(256), 0, stream>>>(x, Win, bin, hA);

    for (int l = 0; l < NLAYER; ++l) {
        // QKV: [16384,256]bf16 @ [256,768] -> bf16 qkv
        gemm_kernel<0><<<dim3(128, 6), dim3(256), 0, stream>>>(
            hA, wqkv + (size_t)l * 768 * 256, bqkv + l * 768, qkv, MTOK, 768, 256);
        // flash attention (one block per (b,h))
        attn_kernel<<<dim3(256), dim3(1024), 0, stream>>>(qkv, mask, ao);
        // Wo + residual + LN1 fused: hB = LN(hA + ao@Wo + bo)
        gemm_ln_kernel<0><<<dim3(MTOK / 64), dim3(256), 0, stream>>>(
            ao, wot + (size_t)l * 65536, bo + l * 256, hA,
            g1 + l * 256, b1 + l * 256, hB, nullptr, 256);
        // FF1: relu(hB@W1 + c1) -> bf16 ffT
        gemm_kernel<1><<<dim3(128, 8), dim3(256), 0, stream>>>(
            hB, w1t + (size_t)l * 262144, c1 + l * 1024, ffT, MTOK, 1024, 256);
        // FF2 + residual + LN2 fused: hA = LN(hB + ffT@W2 + c2)  (last -> d_out)
        if (l == 2) {
            gemm_ln_kernel<1><<<dim3(MTOK / 64), dim3(256), 0, stream>>>(
                ffT, w2t + (size_t)l * 262144, c2 + l * 256, hB,
                g2 + l * 256, b2 + l * 256, nullptr, (float*)d_out, 1024);
        } else {
            gemm_ln_kernel<0><<<dim3(MTOK / 64), dim3(256), 0, stream>>>(
                ffT, w2t + (size_t)l * 262144, c2 + l * 256, hB,
                g2 + l * 256, b2 + l * 256, hA, nullptr, 1024);
        }
    }
}

// Round 6
// 366.912 us; speedup vs baseline: 3.4019x; 1.0684x over previous
//
#include <hip/hip_runtime.h>
#include <cstdint>

#define NLAYER 3
#define DMODEL 256
#define NHEAD 8
#define HEADD 32
#define FFDIM 1024
#define BATCH 32
#define SEQ 512
#define MTOK (BATCH*SEQ)   // 16384

typedef __attribute__((ext_vector_type(8))) __bf16 bf16x8;
typedef __attribute__((ext_vector_type(4))) __bf16 bf16x4;
typedef __attribute__((ext_vector_type(4))) float f32x4;
typedef __attribute__((ext_vector_type(16))) float f32x16;

typedef __attribute__((address_space(1))) const uint8_t ga_t;
typedef __attribute__((address_space(3))) uint8_t la_t;
__device__ __forceinline__ void gll16(const void* g, void* l) {
    __builtin_amdgcn_global_load_lds((ga_t*)g, (la_t*)l, 16, 0, 0);
}

// ---------------------------------------------------------------------------
// Fused prep (weight transpose->bf16, bias concat) + input projection.
// Blocks 0..2312: prep as before. Blocks 2313..4360: inproj, 8 rows each.
// ---------------------------------------------------------------------------
__global__ __launch_bounds__(256)
void prep_kernel(const float* __restrict__ Wq, const float* __restrict__ Wk,
                 const float* __restrict__ Wv, const float* __restrict__ Wo,
                 const float* __restrict__ W1, const float* __restrict__ W2,
                 const float* __restrict__ bq, const float* __restrict__ bk,
                 const float* __restrict__ bv,
                 __bf16* __restrict__ wqkv, __bf16* __restrict__ wot,
                 __bf16* __restrict__ w1t, __bf16* __restrict__ w2t,
                 float* __restrict__ bqkv,
                 const float* __restrict__ x, const float* __restrict__ Win,
                 const float* __restrict__ bin, __bf16* __restrict__ h16)
{
    const int bid = blockIdx.x;
    const int tid = threadIdx.x;
    if (bid >= 2313) {
        // ---- input projection: 8 rows per block ----
        const int m0 = (bid - 2313) * 8;
        const float bv_ = bin[tid];
#pragma unroll
        for (int p = 0; p < 8; ++p) {
            const int m = m0 + p;
            const float* xr = x + (size_t)m * 5;
            float acc = bv_;
#pragma unroll
            for (int k = 0; k < 5; ++k) acc += xr[k] * Win[k * DMODEL + tid];
            h16[(size_t)m * DMODEL + tid] = (__bf16)acc;
        }
        return;
    }
    if (bid >= 3 * 768) {
        int idx = (bid - 3 * 768) * 256 + tid;  // 0..2303
        int l = idx / 768, j = idx % 768;
        float v = (j < 256) ? bq[l * 256 + j]
                : (j < 512) ? bk[l * 256 + j - 256]
                            : bv[l * 256 + j - 512];
        bqkv[idx] = v;
        return;
    }
    const int l = bid / 768;
    const int rr = bid % 768;
    const float* src; __bf16* dst; int K, N, t;
    if (rr < 192) {
        int ty = rr >> 6; t = rr & 63;
        src = (ty == 0 ? Wq : ty == 1 ? Wk : Wv) + (size_t)l * 65536;
        dst = wqkv + (size_t)l * 768 * 256 + (size_t)ty * 65536;
        K = 256; N = 256;
    } else if (rr < 256) {
        t = rr - 192; src = Wo + (size_t)l * 65536; dst = wot + (size_t)l * 65536;
        K = 256; N = 256;
    } else if (rr < 512) {
        t = rr - 256; src = W1 + (size_t)l * 262144; dst = w1t + (size_t)l * 262144;
        K = 256; N = 1024;
    } else {
        t = rr - 512; src = W2 + (size_t)l * 262144; dst = w2t + (size_t)l * 262144;
        K = 1024; N = 256;
    }
    const int tn = N >> 5;
    const int tk = t / tn, tj = t % tn;
    __shared__ float tile[32][33];
    const int c = tid & 31, rbase = tid >> 5;  // rbase 0..7
#pragma unroll
    for (int p = 0; p < 4; ++p) {
        int kr = rbase + p * 8;
        tile[kr][c] = src[(size_t)(tk * 32 + kr) * N + tj * 32 + c];
    }
    __syncthreads();
#pragma unroll
    for (int p = 0; p < 4; ++p) {
        int nr = rbase + p * 8;
        dst[(size_t)(tj * 32 + nr) * K + tk * 32 + c] = (__bf16)tile[c][nr];
    }
}

// ---------------------------------------------------------------------------
// MFMA bf16 GEMM with global_load_lds staging + XOR chunk swizzle.
// 128x128 tile, BK=64, 256 threads (4 waves, 2x2 of 64x64). bf16 out.
// Used for QKV (N=768) and FF1 (N=1024, RELU).
// ---------------------------------------------------------------------------
template<int RELU>
__global__ __launch_bounds__(256, 3)
void gemm_kernel(const __bf16* __restrict__ A, const __bf16* __restrict__ Bt,
                 const float* __restrict__ bias,
                 __bf16* __restrict__ C, int M, int N, int K)
{
    __shared__ __bf16 As[128 * 64];
    __shared__ __bf16 Bs[128 * 64];
    const int tid = threadIdx.x;
    const int m0 = blockIdx.x * 128;
    const int n0 = blockIdx.y * 128;
    const int lane = tid & 63;
    const int wave = tid >> 6;
    const int wm = (wave & 1) * 64;
    const int wn = (wave >> 1) * 64;
    const int fr = lane & 15;
    const int quad = lane >> 4;
    const int lr = lane >> 3;             // row-within-8 for staging
    const int qg = (lane & 7) ^ lr;       // swizzled source chunk

    const __bf16* Ab = A  + (size_t)(m0 + wave * 32 + lr) * K + qg * 8;
    const __bf16* Bb = Bt + (size_t)(n0 + wave * 32 + lr) * K + qg * 8;

    f32x4 acc[4][4];
#pragma unroll
    for (int i = 0; i < 4; ++i)
#pragma unroll
        for (int j = 0; j < 4; ++j)
#pragma unroll
            for (int r = 0; r < 4; ++r) acc[i][j][r] = 0.f;

    const int frs = fr & 7;

    for (int k0 = 0; k0 < K; k0 += 64) {
#pragma unroll
        for (int j = 0; j < 4; ++j) {
            gll16(Ab + (size_t)j * 8 * K + k0, As + (wave * 4 + j) * 512);
            gll16(Bb + (size_t)j * 8 * K + k0, Bs + (wave * 4 + j) * 512);
        }
        __syncthreads();
#pragma unroll
        for (int kk = 0; kk < 2; ++kk) {
            bf16x8 af[4], bfr[4];
#pragma unroll
            for (int i = 0; i < 4; ++i) {
                int row = wm + i * 16 + fr;
                af[i] = *(const bf16x8*)(As + row * 64 + (((kk * 4 + quad) ^ frs) * 8));
            }
#pragma unroll
            for (int j = 0; j < 4; ++j) {
                int row = wn + j * 16 + fr;
                bfr[j] = *(const bf16x8*)(Bs + row * 64 + (((kk * 4 + quad) ^ frs) * 8));
            }
#pragma unroll
            for (int i = 0; i < 4; ++i)
#pragma unroll
                for (int j = 0; j < 4; ++j)
                    acc[i][j] = __builtin_amdgcn_mfma_f32_16x16x32_bf16(
                        af[i], bfr[j], acc[i][j], 0, 0, 0);
        }
        __syncthreads();
    }

#pragma unroll
    for (int i = 0; i < 4; ++i) {
#pragma unroll
        for (int j = 0; j < 4; ++j) {
            const int gc = n0 + wn + j * 16 + fr;
            const float bv = bias[gc];
#pragma unroll
            for (int r = 0; r < 4; ++r) {
                const int gr = m0 + wm + i * 16 + quad * 4 + r;
                float v = acc[i][j][r] + bv;
                if (RELU) v = fmaxf(v, 0.f);
                C[(size_t)gr * N + gc] = (__bf16)v;
            }
        }
    }
}

// ---------------------------------------------------------------------------
// Fused GEMM + residual + LayerNorm, N=256 (whole rows per block).
// 32x256 tile, 256 threads = 4 waves (each 32x64), grid M/32 = 512 blocks
// -> 2 blocks/CU (the round-5 64x256 version was grid=256 = 1 block/CU,
//    which exposed every staging drain; this is the fix).
// LDS: As 4 KB + Bs 32 KB + red 1 KB = 37 KB.
// ---------------------------------------------------------------------------
template<int LAST>
__global__ __launch_bounds__(256, 4)
void gemm_ln_kernel(const __bf16* __restrict__ A, const __bf16* __restrict__ Bt,
                    const float* __restrict__ bias, const __bf16* __restrict__ res,
                    const float* __restrict__ g, const float* __restrict__ be,
                    __bf16* __restrict__ out16, float* __restrict__ out32, int K)
{
    __shared__ __bf16 As[32 * 64];    //  4 KB
    __shared__ __bf16 Bs[256 * 64];   // 32 KB
    __shared__ float red[32 * 8];     //  1 KB  (row -> 4x {sum, sumsq})
    const int tid = threadIdx.x;
    const int m0 = blockIdx.x * 32;
    const int lane = tid & 63;
    const int wave = tid >> 6;            // 0..3
    const int wn = wave * 64;
    const int fr = lane & 15;
    const int quad = lane >> 4;
    const int lr = lane >> 3;
    const int qg = (lane & 7) ^ lr;
    const int frs = fr & 7;

    const __bf16* Ab = A  + (size_t)(m0 + wave * 8 + lr) * K + qg * 8;
    const __bf16* Bb = Bt + (size_t)(wave * 64 + lr) * K + qg * 8;

    f32x4 acc[2][4];
#pragma unroll
    for (int i = 0; i < 2; ++i)
#pragma unroll
        for (int j = 0; j < 4; ++j)
#pragma unroll
            for (int r = 0; r < 4; ++r) acc[i][j][r] = 0.f;

    for (int k0 = 0; k0 < K; k0 += 64) {
        gll16(Ab + k0, As + wave * 512);
#pragma unroll
        for (int p = 0; p < 8; ++p)
            gll16(Bb + (size_t)p * 8 * K + k0, Bs + (wave * 8 + p) * 512);
        __syncthreads();
#pragma unroll
        for (int kk = 0; kk < 2; ++kk) {
            bf16x8 af[2], bfr[4];
#pragma unroll
            for (int i = 0; i < 2; ++i) {
                int row = i * 16 + fr;
                af[i] = *(const bf16x8*)(As + row * 64 + (((kk * 4 + quad) ^ frs) * 8));
            }
#pragma unroll
            for (int j = 0; j < 4; ++j) {
                int row = wn + j * 16 + fr;
                bfr[j] = *(const bf16x8*)(Bs + row * 64 + (((kk * 4 + quad) ^ frs) * 8));
            }
#pragma unroll
            for (int i = 0; i < 2; ++i)
#pragma unroll
                for (int j = 0; j < 4; ++j)
                    acc[i][j] = __builtin_amdgcn_mfma_f32_16x16x32_bf16(
                        af[i], bfr[j], acc[i][j], 0, 0, 0);
        }
        __syncthreads();
    }

    // ---- epilogue: v = acc + bias + res; per-row LN over 256 cols ----
    float bv[4];
#pragma unroll
    for (int j = 0; j < 4; ++j) bv[j] = bias[wn + j * 16 + fr];

#pragma unroll
    for (int i = 0; i < 2; ++i) {
#pragma unroll
        for (int r = 0; r < 4; ++r) {
            const int row = i * 16 + quad * 4 + r;     // 0..31
            float ps = 0.f, pq = 0.f;
#pragma unroll
            for (int j = 0; j < 4; ++j) {
                const int gc = wn + j * 16 + fr;
                float v = acc[i][j][r] + bv[j]
                        + (float)res[(size_t)(m0 + row) * DMODEL + gc];
                acc[i][j][r] = v;
                ps += v;
                pq += v * v;
            }
#pragma unroll
            for (int off = 1; off < 16; off <<= 1) {
                ps += __shfl_xor(ps, off, 64);
                pq += __shfl_xor(pq, off, 64);
            }
            if (fr == 0) {
                red[row * 8 + wave * 2]     = ps;
                red[row * 8 + wave * 2 + 1] = pq;
            }
        }
    }
    __syncthreads();

#pragma unroll
    for (int i = 0; i < 2; ++i) {
#pragma unroll
        for (int r = 0; r < 4; ++r) {
            const int row = i * 16 + quad * 4 + r;
            f32x4 a = *(const f32x4*)(red + row * 8);
            f32x4 b2 = *(const f32x4*)(red + row * 8 + 4);
            const float s  = a[0] + a[2] + b2[0] + b2[2];
            const float sq = a[1] + a[3] + b2[1] + b2[3];
            const float mu = s * (1.f / DMODEL);
            const float var = sq * (1.f / DMODEL) - mu * mu;
            const float rs = rsqrtf(var + 1e-5f);
#pragma unroll
            for (int j = 0; j < 4; ++j) {
                const int gc = wn + j * 16 + fr;
                float y = (acc[i][j][r] - mu) * rs * g[gc] + be[gc];
                if (LAST) out32[(size_t)(m0 + row) * DMODEL + gc] = y;
                else      out16[(size_t)(m0 + row) * DMODEL + gc] = (__bf16)y;
            }
        }
    }
}

// ---------------------------------------------------------------------------
// MFMA flash attention, 32x32 tiles. One block per (b,h): grid=256, 1024 thr
// = 16 waves, each wave owns 32 queries. (unchanged)
// ---------------------------------------------------------------------------
__global__ __launch_bounds__(1024)
void attn_kernel(const __bf16* __restrict__ qkv, const int* __restrict__ mask,
                 __bf16* __restrict__ ao)
{
    __shared__ __bf16 Ks[512 * 40];      // 40960 B
    __shared__ __bf16 Vt[32 * 520];      // 33280 B
    __shared__ __bf16 Pq[16 * 32 * 40];  // 40960 B
    __shared__ float maskadd[512];       //  2048 B

    const int b = blockIdx.x >> 3;
    const int h = blockIdx.x & 7;
    const int t = threadIdx.x;
    const int lane = t & 63;
    const int wave = t >> 6;             // 0..15
    const int cl = lane & 31;
    const int kh = lane >> 5;
    const float scale = 0.17677669529663687f;  // 1/sqrt(32)

    const size_t base = (size_t)b * SEQ * 768;

#pragma unroll
    for (int p = 0; p < 2; ++p) {
        int idx = p * 1024 + t;          // 0..2047
        int key = idx >> 2, ch = idx & 3;
        bf16x8 kv = *(const bf16x8*)(qkv + base + (size_t)key * 768 + 256 + h * 32 + ch * 8);
        *(bf16x8*)(Ks + key * 40 + ch * 8) = kv;
        bf16x8 vv = *(const bf16x8*)(qkv + base + (size_t)key * 768 + 512 + h * 32 + ch * 8);
#pragma unroll
        for (int j = 0; j < 8; ++j) Vt[(ch * 8 + j) * 520 + key] = vv[j];
    }
    if (t < 512) maskadd[t] = mask[b * SEQ + t] ? -1e30f : 0.f;
    __syncthreads();

    const int q0 = wave * 32;
    const __bf16* qrow = qkv + base + (size_t)(q0 + cl) * 768 + h * 32;
    bf16x8 qf0 = *(const bf16x8*)(qrow + kh * 8);
    bf16x8 qf1 = *(const bf16x8*)(qrow + 16 + kh * 8);

    f32x16 oacc;
#pragma unroll
    for (int i = 0; i < 16; ++i) oacc[i] = 0.f;
    float lsum = 0.f;
    __bf16* Pw = Pq + wave * 32 * 40;

    for (int kt = 0; kt < SEQ; kt += 32) {
        bf16x8 kf0 = *(const bf16x8*)(Ks + (kt + cl) * 40 + kh * 8);
        bf16x8 kf1 = *(const bf16x8*)(Ks + (kt + cl) * 40 + 16 + kh * 8);
        f32x16 s;
#pragma unroll
        for (int i = 0; i < 16; ++i) s[i] = 0.f;
        s = __builtin_amdgcn_mfma_f32_32x32x16_bf16(kf0, qf0, s, 0, 0, 0);
        s = __builtin_amdgcn_mfma_f32_32x32x16_bf16(kf1, qf1, s, 0, 0, 0);
        float pv[16];
#pragma unroll
        for (int g = 0; g < 4; ++g) {
            f32x4 mv = *(const f32x4*)(maskadd + kt + 8 * g + 4 * kh);
#pragma unroll
            for (int r = 0; r < 4; ++r) {
                float e = __expf(s[g * 4 + r] * scale + mv[r]);
                pv[g * 4 + r] = e;
                lsum += e;
            }
        }
#pragma unroll
        for (int g = 0; g < 4; ++g) {
            bf16x4 pb;
#pragma unroll
            for (int r = 0; r < 4; ++r) pb[r] = (__bf16)pv[g * 4 + r];
            *(bf16x4*)(Pw + cl * 40 + 8 * g + 4 * kh) = pb;
        }
        bf16x8 pf0 = *(const bf16x8*)(Pw + cl * 40 + kh * 8);
        bf16x8 pf1 = *(const bf16x8*)(Pw + cl * 40 + 16 + kh * 8);
        bf16x8 vf0 = *(const bf16x8*)(Vt + cl * 520 + kt + kh * 8);
        bf16x8 vf1 = *(const bf16x8*)(Vt + cl * 520 + kt + 16 + kh * 8);
        oacc = __builtin_amdgcn_mfma_f32_32x32x16_bf16(vf0, pf0, oacc, 0, 0, 0);
        oacc = __builtin_amdgcn_mfma_f32_32x32x16_bf16(vf1, pf1, oacc, 0, 0, 0);
    }

    lsum += __shfl_xor(lsum, 32);
    const float inv = (lsum > 0.f) ? 1.f / lsum : 0.f;
    __bf16* orow = ao + (size_t)(b * SEQ + q0 + cl) * DMODEL + h * 32;
#pragma unroll
    for (int g = 0; g < 4; ++g) {
        bf16x4 w;
#pragma unroll
        for (int r = 0; r < 4; ++r) w[r] = (__bf16)(oacc[g * 4 + r] * inv);
        *(bf16x4*)(orow + 8 * g + 4 * kh) = w;
    }
}

// ---------------------------------------------------------------------------
extern "C" void kernel_launch(void* const* d_in, const int* in_sizes, int n_in,
                              void* d_out, int out_size, void* d_ws, size_t ws_size,
                              hipStream_t stream)
{
    const float* x   = (const float*)d_in[0];
    const int*   mask= (const int*)d_in[1];
    const float* Win = (const float*)d_in[2];
    const float* bin = (const float*)d_in[3];
    const float* Wq  = (const float*)d_in[4];
    const float* bq  = (const float*)d_in[5];
    const float* Wk  = (const float*)d_in[6];
    const float* bk  = (const float*)d_in[7];
    const float* Wv  = (const float*)d_in[8];
    const float* bv  = (const float*)d_in[9];
    const float* Wo  = (const float*)d_in[10];
    const float* bo  = (const float*)d_in[11];
    const float* g1  = (const float*)d_in[12];
    const float* b1  = (const float*)d_in[13];
    const float* W1  = (const float*)d_in[14];
    const float* c1  = (const float*)d_in[15];
    const float* W2  = (const float*)d_in[16];
    const float* c2  = (const float*)d_in[17];
    const float* g2  = (const float*)d_in[18];
    const float* b2  = (const float*)d_in[19];

    char* ws = (char*)d_ws;
    size_t off = 0;
    auto alloc = [&](size_t bytes) -> void* {
        void* p = ws + off;
        off += (bytes + 255) & ~(size_t)255;
        return p;
    };
    __bf16* hA   = (__bf16*)alloc((size_t)MTOK * 256 * 2);  // 8 MB (residual s_l)
    __bf16* hB   = (__bf16*)alloc((size_t)MTOK * 256 * 2);  // 8 MB (LN1 out t_l)
    __bf16* u    = (__bf16*)alloc((size_t)MTOK * 1024 * 2); // 32 MB (qkv / ff union)
    __bf16* qkv  = u;
    __bf16* ffT  = u;
    __bf16* ao   = (__bf16*)alloc((size_t)MTOK * 256 * 2);  // 8 MB
    __bf16* wqkv = (__bf16*)alloc((size_t)3 * 768 * 256 * 2);
    __bf16* wot  = (__bf16*)alloc((size_t)3 * 256 * 256 * 2);
    __bf16* w1t  = (__bf16*)alloc((size_t)3 * 1024 * 256 * 2);
    __bf16* w2t  = (__bf16*)alloc((size_t)3 * 256 * 1024 * 2);
    float*  bqkv = (float*)alloc((size_t)3 * 768 * 4);

    // prep + inproj fused: 2313 prep blocks + 2048 inproj blocks
    prep_kernel<<<dim3(2313 + MTOK / 8), dim3(256), 0, stream>>>(
        Wq, Wk, Wv, Wo, W1, W2, bq, bk, bv, wqkv, wot, w1t, w2t, bqkv,
        x, Win, bin, hA);

    for (int l = 0; l < NLAYER; ++l) {
        // QKV: [16384,256]bf16 @ [256,768] -> bf16 qkv
        gemm_kernel<0><<<dim3(128, 6), dim3(256), 0, stream>>>(
            hA, wqkv + (size_t)l * 768 * 256, bqkv + l * 768, qkv, MTOK, 768, 256);
        // flash attention (one block per (b,h))
        attn_kernel<<<dim3(256), dim3(1024), 0, stream>>>(qkv, mask, ao);
        // Wo + residual + LN1 fused: hB = LN(hA + ao@Wo + bo)
        gemm_ln_kernel<0><<<dim3(MTOK / 32), dim3(256), 0, stream>>>(
            ao, wot + (size_t)l * 65536, bo + l * 256, hA,
            g1 + l * 256, b1 + l * 256, hB, nullptr, 256);
        // FF1: relu(hB@W1 + c1) -> bf16 ffT
        gemm_kernel<1><<<dim3(128, 8), dim3(256), 0, stream>>>(
            hB, w1t + (size_t)l * 262144, c1 + l * 1024, ffT, MTOK, 1024, 256);
        // FF2 + residual + LN2 fused: hA = LN(hB + ffT@W2 + c2)  (last -> d_out)
        if (l == 2) {
            gemm_ln_kernel<1><<<dim3(MTOK / 32), dim3(256), 0, stream>>>(
                ffT, w2t + (size_t)l * 262144, c2 + l * 256, hB,
                g2 + l * 256, b2 + l * 256, nullptr, (float*)d_out, 1024);
        } else {
            gemm_ln_kernel<0><<<dim3(MTOK / 32), dim3(256), 0, stream>>>(
                ffT, w2t + (size_t)l * 262144, c2 + l * 256, hB,
                g2 + l * 256, b2 + l * 256, hA, nullptr, 1024);
        }
    }
}